// Round 15
// baseline (440.626 us; speedup 1.0000x reference)
//
#include <hip/hip_runtime.h>
#include <stdint.h>

typedef _Float16 f16;
typedef _Float16 f16x8 __attribute__((ext_vector_type(8)));
typedef float    f32x4 __attribute__((ext_vector_type(4)));
typedef unsigned long long u64;

__device__ __forceinline__ void gload16(const void* g, void* l) {
  __builtin_amdgcn_global_load_lds(
      (__attribute__((address_space(1))) void*)g,
      (__attribute__((address_space(3))) void*)l, 16, 0, 0);
}

#define PH_PRE() \
  __builtin_amdgcn_s_barrier(); \
  asm volatile("s_waitcnt lgkmcnt(0)" ::: "memory"); \
  __builtin_amdgcn_sched_barrier(0); \
  __builtin_amdgcn_s_setprio(1);

#define PH_POST() \
  __builtin_amdgcn_s_setprio(0); \
  __builtin_amdgcn_s_barrier(); \
  __builtin_amdgcn_sched_barrier(0);

// ---------------------------------------------------------------------------
// 256x256-tile 8-phase GEMM (proven). 8 waves, 512 thr, 128KB LDS.
// EPI: 12 = f16 y1=c+bias+xh (->outh2) AND f16 sxy=xh+0.5(c+bias) (->outh,
//      in-place over xh) | 13 = f16 relu(c+bias) | 17 = qkv head-major
// ---------------------------------------------------------------------------
#define MFMA_QUAD(q, af) \
  _Pragma("unroll") for (int m2 = 0; m2 < 2; ++m2) \
  _Pragma("unroll") for (int nt = 0; nt < 4; ++nt) \
  _Pragma("unroll") for (int kk = 0; kk < 2; ++kk) \
    acc[(q)*2 + m2][nt] = __builtin_amdgcn_mfma_f32_16x16x32_f16( \
        af[m2][kk], bf[nt][kk], acc[(q)*2 + m2][nt], 0, 0, 0);

#define RD_A(dst, abase, q2) \
  _Pragma("unroll") for (int m2 = 0; m2 < 2; ++m2) \
  _Pragma("unroll") for (int kk = 0; kk < 2; ++kk) { \
    const int lr = (q2)*32 + m2*16 + l15; \
    dst[m2][kk] = *(const f16x8*)&abase[lr*64 + (((kk*4 + l4) ^ (lr & 7)) << 3)]; }

#define RD_B(bbase) \
  _Pragma("unroll") for (int nt = 0; nt < 4; ++nt) \
  _Pragma("unroll") for (int kk = 0; kk < 2; ++kk) { \
    const int lr = brow + nt*16 + l15; \
    bf[nt][kk] = *(const f16x8*)&bbase[lr*64 + (((kk*4 + l4) ^ (lr & 7)) << 3)]; }

template<int EPI>
__global__ __launch_bounds__(512, 2)
void gemm256(const f16* __restrict__ A, int lda,
             const f16* __restrict__ Bt, int ldb,
             int K, int N,
             float* __restrict__ outf, f16* __restrict__ outh,
             f16* __restrict__ outh2,
             const float* __restrict__ bias,
             const f16* __restrict__ xh)
{
  __shared__ __align__(16) f16 lds[65536];   // 128 KiB
  const int tid = threadIdx.x, lane = tid & 63;
  const int wid = tid >> 6;
  const int wm = wid >> 2, wn = wid & 3;
  const int l15 = lane & 15, l4 = lane >> 4;

  const int gx = gridDim.x;
  int lid = blockIdx.y * gx + blockIdx.x;
  const int cpx = (gx * gridDim.y) >> 3;
  lid = (lid & 7) * cpx + (lid >> 3);
  const long bm0 = (long)(lid / gx) * 256;
  const long bn0 = (long)(lid % gx) * 256;

  const int rs = tid >> 3, cs = tid & 7;
  const int cg = cs ^ (rs & 7);
  const int nkt = K >> 6;                    // pow2, >= 8
  const int nmask = nkt - 1;

  auto stageA = [&](int d, int half, int kt) {
    f16* dst = &lds[(d * 4 + half) * 8192];
    const long kb = (long)kt * 64 + cg * 8;
    const f16* src = A + (bm0 + half * 128) * lda + kb;
#pragma unroll
    for (int rr = 0; rr < 2; ++rr) {
      const int row = rs + rr * 64;
      gload16(src + (long)row * lda, dst + row * 64 + cs * 8);
    }
  };
  auto stageB = [&](int d, int half, int kt) {
    f16* dst = &lds[(d * 4 + 2 + half) * 8192];
    const long kb = (long)kt * 64 + cg * 8;
    const f16* src = Bt + (bn0 + half * 128) * ldb + kb;
#pragma unroll
    for (int rr = 0; rr < 2; ++rr) {
      const int row = rs + rr * 64;
      gload16(src + (long)row * ldb, dst + row * 64 + cs * 8);
    }
  };

  const f16* aBase0 = &lds[(0 + wm) * 8192];
  const f16* aBase1 = &lds[(4 + wm) * 8192];
  const f16* bBase0 = &lds[(2 + (wn >> 1)) * 8192];
  const f16* bBase1 = &lds[(6 + (wn >> 1)) * 8192];
  const int brow = (wn & 1) * 64;

  f32x4 acc[8][4];
#pragma unroll
  for (int i = 0; i < 8; ++i)
#pragma unroll
    for (int j = 0; j < 4; ++j) acc[i][j] = f32x4{0.f, 0.f, 0.f, 0.f};
  f16x8 bf[4][2], afA[2][2], afB[2][2];

  stageB(0, 0, 0); stageB(0, 1, 0); stageA(0, 0, 0); stageA(0, 1, 0);
  asm volatile("s_waitcnt vmcnt(4)" ::: "memory");
  stageB(1, 0, 1); stageB(1, 1, 1); stageA(1, 0, 1);
  asm volatile("s_waitcnt vmcnt(6)" ::: "memory");
  __builtin_amdgcn_s_barrier();
  __builtin_amdgcn_sched_barrier(0);

  for (int j = 0; j < nkt; j += 2) {
    const int t2 = (j + 2) & nmask, t3 = (j + 3) & nmask;
    RD_B(bBase0); RD_A(afA, aBase0, 0);
    stageA(1, 1, (j + 1) & nmask);
    asm volatile("s_waitcnt lgkmcnt(8)" ::: "memory");
    PH_PRE(); MFMA_QUAD(0, afA); PH_POST();
    RD_A(afB, aBase0, 1); RD_A(afA, aBase0, 2);
    stageB(0, 0, t2);
    PH_PRE(); MFMA_QUAD(1, afB); PH_POST();
    RD_A(afB, aBase0, 3);
    stageB(0, 1, t2);
    PH_PRE(); MFMA_QUAD(2, afA); PH_POST();
    stageA(0, 0, t2);
    asm volatile("s_waitcnt vmcnt(6)" ::: "memory");
    PH_PRE(); MFMA_QUAD(3, afB); PH_POST();
    RD_B(bBase1); RD_A(afA, aBase1, 0);
    stageA(0, 1, t2);
    asm volatile("s_waitcnt lgkmcnt(8)" ::: "memory");
    PH_PRE(); MFMA_QUAD(0, afA); PH_POST();
    RD_A(afB, aBase1, 1); RD_A(afA, aBase1, 2);
    stageB(1, 0, t3);
    PH_PRE(); MFMA_QUAD(1, afB); PH_POST();
    RD_A(afB, aBase1, 3);
    stageB(1, 1, t3);
    PH_PRE(); MFMA_QUAD(2, afA); PH_POST();
    stageA(1, 0, t3);
    asm volatile("s_waitcnt vmcnt(6)" ::: "memory");
    PH_PRE(); MFMA_QUAD(3, afB); PH_POST();
  }
  asm volatile("s_waitcnt vmcnt(0)" ::: "memory");

#pragma unroll
  for (int mt = 0; mt < 8; ++mt)
#pragma unroll
    for (int nt = 0; nt < 4; ++nt)
#pragma unroll
      for (int r = 0; r < 4; ++r) {
        const long grow = bm0 + wm * 128 + mt * 16 + l4 * 4 + r;
        const long gcol = bn0 + wn * 64 + nt * 16 + l15;
        const float c = acc[mt][nt][r];
        if constexpr (EPI == 12) {
          const long idx = grow * (long)N + gcol;
          const float t = c + bias[gcol];
          const float xx = (float)xh[idx];
          outh2[idx] = (f16)(t + xx);         // y1 (f16)
          outh[idx]  = (f16)(xx + 0.5f * t);  // sxy = 0.5*(x+y1), in-place
        } else if constexpr (EPI == 13) {
          const long idx = grow * (long)N + gcol;
          outh[idx] = (f16)fmaxf(c + bias[gcol], 0.f);
        } else if constexpr (EPI == 17) {
          const int bb = (int)(grow >> 12), tt = (int)(grow & 4095);
          const int hcol = (int)(bn0 >> 6) + wn;
          const int is_v = hcol >> 3, h = hcol & 7;
          f16* base = is_v ? outh2 : outh;
          base[(((long)bb * 8 + h) * 4096 + tt) * 64 + nt * 16 + l15] = (f16)c;
        }
      }
}

// ---------------------------------------------------------------------------
// FFN2 8-phase GEMM (proven): BM=256 x BN=128, BK=64, K=2048, 8 waves,
// 96KB LDS. out = sxy + 0.5*(c + bias).
// ---------------------------------------------------------------------------
#define RD2_B(bbase) \
  _Pragma("unroll") for (int nt = 0; nt < 4; ++nt) \
  _Pragma("unroll") for (int kk = 0; kk < 2; ++kk) { \
    const int lr = brow + nt*16 + l15; \
    bf[nt][kk] = *(const f16x8*)&bbase[lr*64 + (((kk*4 + l4) ^ (lr & 7)) << 3)]; }

#define RD2_A(dst, abase, mt) \
  _Pragma("unroll") for (int kk = 0; kk < 2; ++kk) { \
    const int lr = arow + (mt)*16 + l15; \
    dst[kk] = *(const f16x8*)&abase[lr*64 + (((kk*4 + l4) ^ (lr & 7)) << 3)]; }

#define MFMA_Q1(mt, af) \
  _Pragma("unroll") for (int nt = 0; nt < 4; ++nt) \
  _Pragma("unroll") for (int kk = 0; kk < 2; ++kk) \
    acc[mt][nt] = __builtin_amdgcn_mfma_f32_16x16x32_f16( \
        af[kk], bf[nt][kk], acc[mt][nt], 0, 0, 0);

__global__ __launch_bounds__(512, 2)
void ffn2_8ph(const f16* __restrict__ A, const f16* __restrict__ Bt,
              const f16* __restrict__ sxyh, const float* __restrict__ bias,
              float* __restrict__ outf)
{
  __shared__ __align__(16) f16 lds[49152];   // 96 KiB: 6 x 16KB regions
  const int tid = threadIdx.x, lane = tid & 63;
  const int wid = tid >> 6;
  const int wm = wid >> 1, wn = wid & 1;     // 4M x 2N
  const int l15 = lane & 15, l4 = lane >> 4;

  const int gx = gridDim.x;                  // 4
  int lid = blockIdx.y * gx + blockIdx.x;
  const int cpx = (gx * gridDim.y) >> 3;
  lid = (lid & 7) * cpx + (lid >> 3);
  const long bm0 = (long)(lid / gx) * 256;
  const long bn0 = (long)(lid % gx) * 128;

  const int rs = tid >> 3, cs = tid & 7;
  const int cg = cs ^ (rs & 7);
  const int nmask = 31;                      // nkt = 32

  auto stageA = [&](int d, int half, int kt) {
    f16* dst = &lds[(d * 3 + half) * 8192];
    const long kb = (long)kt * 64 + cg * 8;
    const f16* src = A + (bm0 + half * 128) * 2048 + kb;
#pragma unroll
    for (int rr = 0; rr < 2; ++rr) {
      const int row = rs + rr * 64;
      gload16(src + (long)row * 2048, dst + row * 64 + cs * 8);
    }
  };
  auto stageB = [&](int d, int kt) {
    f16* dst = &lds[(d * 3 + 2) * 8192];
    const long kb = (long)kt * 64 + cg * 8;
    const f16* src = Bt + bn0 * 2048 + kb;
#pragma unroll
    for (int rr = 0; rr < 2; ++rr) {
      const int row = rs + rr * 64;
      gload16(src + (long)row * 2048, dst + row * 64 + cs * 8);
    }
  };

  const f16* aBase0 = &lds[(0 + (wm >> 1)) * 8192];
  const f16* aBase1 = &lds[(3 + (wm >> 1)) * 8192];
  const f16* bBase0 = &lds[2 * 8192];
  const f16* bBase1 = &lds[5 * 8192];
  const int arow = (wm & 1) * 64;
  const int brow = wn * 64;

  f32x4 acc[4][4];
#pragma unroll
  for (int i = 0; i < 4; ++i)
#pragma unroll
    for (int j = 0; j < 4; ++j) acc[i][j] = f32x4{0.f, 0.f, 0.f, 0.f};
  f16x8 bf[4][2], afA[2], afB[2];

  // prologue: t0 full, t1 full; wait t0
  stageB(0, 0); stageA(0, 0, 0); stageA(0, 1, 0);
  stageB(1, 1); stageA(1, 0, 1); stageA(1, 1, 1);
  asm volatile("s_waitcnt vmcnt(6)" ::: "memory");
  __builtin_amdgcn_s_barrier();
  __builtin_amdgcn_sched_barrier(0);

  for (int j = 0; j < 32; j += 2) {
    const int t2 = (j + 2) & nmask, t3 = (j + 3) & nmask;
    // ---- tile j (buf0) ----
    RD2_B(bBase0); RD2_A(afA, aBase0, 0);
    asm volatile("s_waitcnt lgkmcnt(8)" ::: "memory");
    PH_PRE(); MFMA_Q1(0, afA); PH_POST();
    RD2_A(afB, aBase0, 1); RD2_A(afA, aBase0, 2);
    stageB(0, t2);
    PH_PRE(); MFMA_Q1(1, afB); PH_POST();
    RD2_A(afB, aBase0, 3);
    PH_PRE(); MFMA_Q1(2, afA); PH_POST();
    stageA(0, 0, t2); stageA(0, 1, t2);
    asm volatile("s_waitcnt vmcnt(6)" ::: "memory");
    PH_PRE(); MFMA_Q1(3, afB); PH_POST();
    // ---- tile j+1 (buf1) ----
    RD2_B(bBase1); RD2_A(afA, aBase1, 0);
    asm volatile("s_waitcnt lgkmcnt(8)" ::: "memory");
    PH_PRE(); MFMA_Q1(0, afA); PH_POST();
    RD2_A(afB, aBase1, 1); RD2_A(afA, aBase1, 2);
    stageB(1, t3);
    PH_PRE(); MFMA_Q1(1, afB); PH_POST();
    RD2_A(afB, aBase1, 3);
    PH_PRE(); MFMA_Q1(2, afA); PH_POST();
    stageA(1, 0, t3); stageA(1, 1, t3);
    asm volatile("s_waitcnt vmcnt(6)" ::: "memory");
    PH_PRE(); MFMA_Q1(3, afB); PH_POST();
  }
  asm volatile("s_waitcnt vmcnt(0)" ::: "memory");

#pragma unroll
  for (int mt = 0; mt < 4; ++mt)
#pragma unroll
    for (int nt = 0; nt < 4; ++nt)
#pragma unroll
      for (int r = 0; r < 4; ++r) {
        const long grow = bm0 + wm * 64 + mt * 16 + l4 * 4 + r;
        const long gcol = bn0 + wn * 64 + nt * 16 + l15;
        const long idx = grow * 512 + gcol;
        outf[idx] = (float)sxyh[idx] + 0.5f * (acc[mt][nt][r] + bias[gcol]);
      }
}

// ---------------------------------------------------------------------------
// LN1: reads fp32 x, writes hh = (f16)LN(x) (stride 512) AND xh = (f16)x.
// ---------------------------------------------------------------------------
__global__ __launch_bounds__(256)
void ln_x16_kernel(const float* __restrict__ in, const float* __restrict__ gam,
                   const float* __restrict__ bet, f16* __restrict__ hh,
                   f16* __restrict__ xh)
{
  const long row = (long)blockIdx.x * 4 + (threadIdx.x >> 6);
  const int lane = threadIdx.x & 63;
  const float4* p = (const float4*)(in + row * 512);
  const float4 a = p[lane * 2], b = p[lane * 2 + 1];
  float xv[8] = {a.x, a.y, a.z, a.w, b.x, b.y, b.z, b.w};
  float s = 0.f;
#pragma unroll
  for (int i = 0; i < 8; ++i) s += xv[i];
#pragma unroll
  for (int m = 32; m; m >>= 1) s += __shfl_xor(s, m);
  const float mean = s * (1.f / 512.f);
  float vs = 0.f;
#pragma unroll
  for (int i = 0; i < 8; ++i) { const float d = xv[i] - mean; vs += d * d; }
#pragma unroll
  for (int m = 32; m; m >>= 1) vs += __shfl_xor(vs, m);
  const float rstd = 1.f / sqrtf(vs * (1.f / 512.f) + 1e-5f);
  const float4* gp = (const float4*)gam;
  const float4* bp = (const float4*)bet;
  const float4 g0 = gp[lane * 2], g1 = gp[lane * 2 + 1];
  const float4 b0 = bp[lane * 2], b1 = bp[lane * 2 + 1];
  const float gg[8] = {g0.x, g0.y, g0.z, g0.w, g1.x, g1.y, g1.z, g1.w};
  const float bb[8] = {b0.x, b0.y, b0.z, b0.w, b1.x, b1.y, b1.z, b1.w};
  f16x8 vh, vx;
#pragma unroll
  for (int i = 0; i < 8; ++i) {
    vh[i] = (f16)((xv[i] - mean) * rstd * gg[i] + bb[i]);
    vx[i] = (f16)xv[i];
  }
  *(f16x8*)(hh + row * 512 + lane * 8) = vh;
  *(f16x8*)(xh + row * 512 + lane * 8) = vx;
}

// ---------------------------------------------------------------------------
// LN2 over D=512, f16 input (y1h), f16 output.
// ---------------------------------------------------------------------------
__global__ __launch_bounds__(256)
void ln16_kernel(const f16* __restrict__ in, const float* __restrict__ gam,
                 const float* __restrict__ bet, f16* __restrict__ out)
{
  const long row = (long)blockIdx.x * 4 + (threadIdx.x >> 6);
  const int lane = threadIdx.x & 63;
  const f16x8 v = *(const f16x8*)(in + row * 512 + lane * 8);
  float xv[8];
#pragma unroll
  for (int i = 0; i < 8; ++i) xv[i] = (float)v[i];
  float s = 0.f;
#pragma unroll
  for (int i = 0; i < 8; ++i) s += xv[i];
#pragma unroll
  for (int m = 32; m; m >>= 1) s += __shfl_xor(s, m);
  const float mean = s * (1.f / 512.f);
  float vs = 0.f;
#pragma unroll
  for (int i = 0; i < 8; ++i) { const float d = xv[i] - mean; vs += d * d; }
#pragma unroll
  for (int m = 32; m; m >>= 1) vs += __shfl_xor(vs, m);
  const float rstd = 1.f / sqrtf(vs * (1.f / 512.f) + 1e-5f);
  const float4* gp = (const float4*)gam;
  const float4* bp = (const float4*)bet;
  const float4 g0 = gp[lane * 2], g1 = gp[lane * 2 + 1];
  const float4 b0 = bp[lane * 2], b1 = bp[lane * 2 + 1];
  const float gg[8] = {g0.x, g0.y, g0.z, g0.w, g1.x, g1.y, g1.z, g1.w};
  const float bb[8] = {b0.x, b0.y, b0.z, b0.w, b1.x, b1.y, b1.z, b1.w};
  f16x8 vh;
#pragma unroll
  for (int i = 0; i < 8; ++i)
    vh[i] = (f16)((xv[i] - mean) * rstd * gg[i] + bb[i]);
  *(f16x8*)(out + row * 512 + lane * 8) = vh;
}

// ---------------------------------------------------------------------------
__global__ __launch_bounds__(256)
void transpose_f16(const float* __restrict__ src, f16* __restrict__ dst, int K, int N)
{
  __shared__ float tile[32][33];
  const int tx = threadIdx.x & 31, ty = threadIdx.x >> 5;
  const long k0 = (long)blockIdx.y * 32, n0 = (long)blockIdx.x * 32;
#pragma unroll
  for (int i = 0; i < 4; ++i)
    tile[ty + i * 8][tx] = src[(k0 + ty + i * 8) * N + n0 + tx];
  __syncthreads();
#pragma unroll
  for (int i = 0; i < 4; ++i)
    dst[(n0 + ty + i * 8) * K + k0 + tx] = (f16)tile[tx][ty + i * 8];
}

// ---------------------------------------------------------------------------
// WrT[n][k] fp32 (fixup) + rotTh f16 [i][d] (rhash).
// ---------------------------------------------------------------------------
__global__ __launch_bounds__(256)
void whash_f32(const float* __restrict__ wqk, const float* __restrict__ rot,
               float* __restrict__ WrT, f16* __restrict__ rotTh)
{
  if (blockIdx.x == 0 && blockIdx.y == 0) {
    for (int idx = threadIdx.x; idx < 4096; idx += 256) {
      const int d = idx >> 6, i = idx & 63;
      rotTh[i * 64 + d] = (f16)rot[idx];
    }
  }
  const int kk = blockIdx.x;                     // 0..511
  const int n  = blockIdx.y * 256 + threadIdx.x; // 0..511
  const int h = n >> 6, i = n & 63;
  float s = 0.f;
  for (int d = 0; d < 64; ++d)
    s += wqk[kk * 512 + h * 64 + d] * rot[d * 64 + i];
  WrT[(long)n * 512 + kk] = s;
}

// ---------------------------------------------------------------------------
// rhash4: r = qk . rot^T via MFMA (K=64). bucket = argmax over [r,-r].
// No atomics: packs bucket|col2<<8|col3<<16|flag<<24 into buckets.
// ---------------------------------------------------------------------------
__global__ __launch_bounds__(256)
void rhash4_kernel(const f16* __restrict__ gqk, const f16* __restrict__ rotTh,
                   int* __restrict__ buckets)
{
  const int tid = threadIdx.x, lane = tid & 63, w = tid >> 6;
  const int bh = blockIdx.x >> 5, tb = blockIdx.x & 31;
  const int t0 = tb * 128;
  const int l15 = lane & 15, l4 = lane >> 4;

  f16x8 br[2][4];
#pragma unroll
  for (int kk = 0; kk < 2; ++kk)
#pragma unroll
    for (int nt = 0; nt < 4; ++nt)
      br[kk][nt] = *(const f16x8*)&rotTh[(nt * 16 + l15) * 64 + kk * 32 + l4 * 8];

  const f16* gqb = gqk + ((long)bh * 4096 + t0) * 64;
  f16x8 aq[2][2];
#pragma unroll
  for (int kk = 0; kk < 2; ++kk)
#pragma unroll
    for (int mt = 0; mt < 2; ++mt)
      aq[kk][mt] = *(const f16x8*)&gqb[(long)(w * 32 + mt * 16 + l15) * 64 + kk * 32 + l4 * 8];

  f32x4 acc[2][4];
#pragma unroll
  for (int i = 0; i < 2; ++i)
#pragma unroll
    for (int j = 0; j < 4; ++j) acc[i][j] = f32x4{0.f, 0.f, 0.f, 0.f};
#pragma unroll
  for (int kk = 0; kk < 2; ++kk)
#pragma unroll
    for (int mt = 0; mt < 2; ++mt)
#pragma unroll
      for (int nt = 0; nt < 4; ++nt)
        acc[mt][nt] = __builtin_amdgcn_mfma_f32_16x16x32_f16(aq[kk][mt], br[kk][nt], acc[mt][nt], 0, 0, 0);

#pragma unroll
  for (int mt = 0; mt < 2; ++mt)
#pragma unroll
    for (int r = 0; r < 4; ++r) {
      const float v0 = acc[mt][0][r], v1 = acc[mt][1][r];
      const float v2 = acc[mt][2][r], v3 = acc[mt][3][r];
      unsigned int k0 = (__float_as_uint(fabsf(v0)) & ~63u) | (unsigned int)(63 - l15);
      unsigned int k1 = (__float_as_uint(fabsf(v1)) & ~63u) | (unsigned int)(47 - l15);
      unsigned int k2 = (__float_as_uint(fabsf(v2)) & ~63u) | (unsigned int)(31 - l15);
      unsigned int k3 = (__float_as_uint(fabsf(v3)) & ~63u) | (unsigned int)(15 - l15);
      float ss = v0 * v0 + v1 * v1 + v2 * v2 + v3 * v3;
#pragma unroll
      for (int m = 1; m < 16; m <<= 1) ss += __shfl_xor(ss, m);

      unsigned int mk = max(max(k0, k1), max(k2, k3));
#pragma unroll
      for (int m = 1; m < 16; m <<= 1) mk = max(mk, (unsigned int)__shfl_xor((int)mk, m));
      const unsigned int key1 = mk;
      const int col1 = 63 - (int)(key1 & 63u);
      const float m1f = __uint_as_float(key1 & ~63u);
      const int nt1 = col1 >> 4;
      const float vsel = (nt1 == 0) ? v0 : (nt1 == 1) ? v1 : (nt1 == 2) ? v2 : v3;
      const bool owner = (col1 & 15) == l15;
      const u64 bal = __ballot(owner && (vsel < 0.f));
      const int neg = (int)((bal >> (l4 * 16 + (col1 & 15))) & 1ull);
      const int bucket = col1 + (neg << 6);
      if (owner) {
        if (nt1 == 0) k0 = 0; else if (nt1 == 1) k1 = 0;
        else if (nt1 == 2) k2 = 0; else k3 = 0;
      }
      mk = max(max(k0, k1), max(k2, k3));
#pragma unroll
      for (int m = 1; m < 16; m <<= 1) mk = max(mk, (unsigned int)__shfl_xor((int)mk, m));
      const int col2 = 63 - (int)(mk & 63u);
      const float m2f = __uint_as_float(mk & ~63u);
      {
        const int nt2 = col2 >> 4;
        if ((col2 & 15) == l15) {
          if (nt2 == 0) k0 = 0; else if (nt2 == 1) k1 = 0;
          else if (nt2 == 2) k2 = 0; else k3 = 0;
        }
      }
      mk = max(max(k0, k1), max(k2, k3));
#pragma unroll
      for (int m = 1; m < 16; m <<= 1) mk = max(mk, (unsigned int)__shfl_xor((int)mk, m));
      const int col3 = 63 - (int)(mk & 63u);

      if (l15 == 0) {
        const int row = w * 32 + mt * 16 + l4 * 4 + r;
        const int bht = bh * 4096 + t0 + row;
        const float margin = m1f - m2f;
        const float rms = sqrtf(ss * (1.f / 64.f));
        const int flag = (margin < 0.015f * rms) ? 1 : 0;
        buckets[bht] = bucket | (col2 << 8) | (col3 << 16) | (flag << 24);
      }
    }
}

// ---------------------------------------------------------------------------
// fixup2: scan flag bit; per-wave ballot compaction; exact fp32 re-eval.
// h1 recomputed as exact fp32 LN(x) per flagged row.
// ---------------------------------------------------------------------------
__global__ __launch_bounds__(256)
void fixup2_kernel(const float* __restrict__ x, const float* __restrict__ gam,
                   const float* __restrict__ bet, const float* __restrict__ WrT,
                   int* __restrict__ buckets)
{
  const int wid = (blockIdx.x * 256 + threadIdx.x) >> 6;   // 0..1023
  const int lane = threadIdx.x & 63;
  for (int batch = 0; batch < 4; ++batch) {
    const int base = wid * 256 + batch * 64;
    const int packed = buckets[base + lane];
    u64 bal = __ballot((packed >> 24) & 1);
    while (bal) {
      const int i = (int)__ffsll((long long)bal) - 1;
      bal &= bal - 1;
      const int row = base + i;
      const int pk = __shfl(packed, i);
      const int h = (row >> 12) & 7;
      const long hrow = (long)(row >> 15) * 4096 + (row & 4095);
      // exact LN(x) for this row
      const float4* xp = (const float4*)(x + hrow * 512 + lane * 8);
      const float4 a = xp[0], b = xp[1];
      float xv[8] = {a.x, a.y, a.z, a.w, b.x, b.y, b.z, b.w};
      float s = 0.f;
#pragma unroll
      for (int k = 0; k < 8; ++k) s += xv[k];
#pragma unroll
      for (int m = 32; m; m >>= 1) s += __shfl_xor(s, m);
      const float mean = s * (1.f / 512.f);
      float vs = 0.f;
#pragma unroll
      for (int k = 0; k < 8; ++k) { const float d = xv[k] - mean; vs += d * d; }
#pragma unroll
      for (int m = 32; m; m >>= 1) vs += __shfl_xor(vs, m);
      const float rstd = 1.f / sqrtf(vs * (1.f / 512.f) + 1e-5f);
      const float4* gp = (const float4*)(gam + lane * 8);
      const float4* bp = (const float4*)(bet + lane * 8);
      const float4 g0 = gp[0], g1 = gp[1];
      const float4 bb0 = bp[0], bb1 = bp[1];
      const float gg[8] = {g0.x, g0.y, g0.z, g0.w, g1.x, g1.y, g1.z, g1.w};
      const float bb[8] = {bb0.x, bb0.y, bb0.z, bb0.w, bb1.x, bb1.y, bb1.z, bb1.w};
      float h1[8];
#pragma unroll
      for (int k = 0; k < 8; ++k) h1[k] = (xv[k] - mean) * rstd * gg[k] + bb[k];
      const int cols[3] = { pk & 63, (pk >> 8) & 63, (pk >> 16) & 63 };
      float best = -1e30f; int bi = 999;
#pragma unroll
      for (int c = 0; c < 3; ++c) {
        const int cc = cols[c];
        const float* wp = WrT + ((long)(h * 64 + cc)) * 512 + lane * 8;
        const float4 w0 = *(const float4*)wp;
        const float4 w1 = *(const float4*)(wp + 4);
        float sdot = h1[0] * w0.x + h1[1] * w0.y + h1[2] * w0.z + h1[3] * w0.w
                   + h1[4] * w1.x + h1[5] * w1.y + h1[6] * w1.z + h1[7] * w1.w;
#pragma unroll
        for (int m = 32; m; m >>= 1) sdot += __shfl_xor(sdot, m);
        if (sdot > best || (sdot == best && cc < bi)) { best = sdot; bi = cc; }
        const float ns = -sdot; const int ni = 64 + cc;
        if (ns > best || (ns == best && ni < bi)) { best = ns; bi = ni; }
      }
      if (lane == 0) buckets[row] = bi;
    }
  }
}

// ---------------------------------------------------------------------------
// Stable counting sort by (bucket, t) per bh. sticker[pos] = original t.
// ---------------------------------------------------------------------------
__global__ __launch_bounds__(256)
void sort_kernel(const int* __restrict__ buckets, int* __restrict__ sticker)
{
  __shared__ int bkt[4096];
  __shared__ unsigned int cnts[64][128];
  __shared__ unsigned char rnk[4096];
  __shared__ int tot[128];
  __shared__ int base[128];
  const int bh = blockIdx.x;
  const int tid = threadIdx.x;
  const int lane = tid & 63, wv = tid >> 6;

  for (int i = tid; i < 4096; i += 256) bkt[i] = buckets[(long)bh * 4096 + i] & 127;
  for (int i = tid; i < 64 * 128; i += 256) ((unsigned int*)cnts)[i] = 0u;
  __syncthreads();

  for (int it = 0; it < 16; ++it) {
    const int c = wv * 16 + it;
    const int t = c * 64 + lane;
    const int b = bkt[t];
    unsigned long long m = ~0ull;
#pragma unroll
    for (int k = 0; k < 7; ++k) {
      const bool bit = (b >> k) & 1;
      const unsigned long long bal = __ballot(bit);
      m &= bit ? bal : ~bal;
    }
    const int rk = (int)__popcll(m & ((1ull << lane) - 1ull));
    rnk[t] = (unsigned char)rk;
    if (rk == 0) cnts[c][b] = (unsigned int)__popcll(m);
  }
  __syncthreads();

  if (tid < 128) {
    unsigned int run = 0;
    for (int c = 0; c < 64; ++c) {
      const unsigned int x = cnts[c][tid];
      cnts[c][tid] = run;
      run += x;
    }
    tot[tid] = (int)run;
  }
  __syncthreads();
  if (tid == 0) {
    int run = 0;
    for (int b = 0; b < 128; ++b) { base[b] = run; run += tot[b]; }
  }
  __syncthreads();

  for (int it = 0; it < 16; ++it) {
    const int c = wv * 16 + it;
    const int t = c * 64 + lane;
    const int b = bkt[t];
    const int pos = base[b] + (int)cnts[c][b] + (int)rnk[t];
    sticker[(long)bh * 4096 + pos] = t;
  }
}

// ---------------------------------------------------------------------------
// LSH attention, gather version. Block = 256 thr / 4 waves / 4 chunks.
// ---------------------------------------------------------------------------
__global__ __launch_bounds__(256)
void attn2_kernel(const f16* __restrict__ gqk, const f16* __restrict__ gv,
                  const int* __restrict__ sticker, f16* __restrict__ o)
{
  __shared__ __align__(16) f16 sqk[160 * 64];     // granule-XOR swizzled
  __shared__ __align__(16) f16 sVT[64 * 168];     // [d][key 0..159]
  __shared__ __align__(16) f16 sP[4][32 * 72];
  __shared__ float rnorm[160];
  __shared__ int st[160];

  const int tid = threadIdx.x, lane = tid & 63, w = tid >> 6;
  const int cg = blockIdx.x, bh = blockIdx.y;
  const int b = bh >> 3, h = bh & 7;
  const int p0 = cg * 128 - 32;
  const int l15 = lane & 15, l4 = lane >> 4;

  if (tid < 160) st[tid] = sticker[(long)bh * 4096 + ((p0 + tid) & 4095)] & 4095;
  __syncthreads();

  const f16* gqb = gqk + (long)bh * 4096 * 64;
#pragma unroll
  for (int it = 0; it < 5; ++it) {
    const int idx = it * 256 + tid;
    const int row = idx >> 3, ch = idx & 7;
    const int gsrc = ch ^ (row & 7);
    gload16(gqb + (long)st[row] * 64 + gsrc * 8, &sqk[idx * 8]);
  }

  const f16* gvb = gv + (long)bh * 4096 * 64;
  f16x8 va[5];
#pragma unroll
  for (int i = 0; i < 5; ++i) {
    const int row = w * 40 + i * 8 + (lane >> 3);
    va[i] = *(const f16x8*)&gvb[(long)st[row] * 64 + (lane & 7) * 8];
  }
#pragma unroll
  for (int i = 0; i < 5; ++i) {
    const int row = w * 40 + i * 8 + (lane >> 3);
    const int d0 = (lane & 7) * 8;
#pragma unroll
    for (int e = 0; e < 8; ++e) sVT[(d0 + e) * 168 + row] = va[i][e];
  }
  __syncthreads();

  if (tid < 160) {
    float s = 0.f;
#pragma unroll
    for (int g = 0; g < 8; ++g) {
      const f16x8 v = *(const f16x8*)&sqk[tid * 64 + ((g ^ (tid & 7)) << 3)];
#pragma unroll
      for (int e = 0; e < 8; ++e) { const float f = (float)v[e]; s += f * f; }
    }
    rnorm[tid] = 1.f / fmaxf(sqrtf(s), 1e-12f);
  }
  __syncthreads();

  f32x4 acc[2][4];
#pragma unroll
  for (int i = 0; i < 2; ++i)
#pragma unroll
    for (int j = 0; j < 4; ++j) acc[i][j] = f32x4{0.f, 0.f, 0.f, 0.f};

#pragma unroll
  for (int kk = 0; kk < 2; ++kk) {
    f16x8 aq[2], bk[4];
#pragma unroll
    for (int mt = 0; mt < 2; ++mt) {
      const int row = 32 + w * 32 + mt * 16 + l15;
      const int g = kk * 4 + l4;
      aq[mt] = *(const f16x8*)&sqk[row * 64 + ((g ^ (row & 7)) << 3)];
    }
#pragma unroll
    for (int nt = 0; nt < 4; ++nt) {
      const int row = w * 32 + nt * 16 + l15;
      const int g = kk * 4 + l4;
      bk[nt] = *(const f16x8*)&sqk[row * 64 + ((g ^ (row & 7)) << 3)];
    }
#pragma unroll
    for (int mt = 0; mt < 2; ++mt)
#pragma unroll
      for (int nt = 0; nt < 4; ++nt)
        acc[mt][nt] = __builtin_amdgcn_mfma_f32_16x16x32_f16(aq[mt], bk[nt], acc[mt][nt], 0, 0, 0);
  }

  float rn[4];
#pragma unroll
  for (int nt = 0; nt < 4; ++nt) rn[nt] = rnorm[w * 32 + nt * 16 + l15];

  float pinv[2][4];
#pragma unroll
  for (int mt = 0; mt < 2; ++mt)
#pragma unroll
    for (int r = 0; r < 4; ++r) {
      const int row_i = mt * 16 + l4 * 4 + r;
      float mx = -1e30f;
#pragma unroll
      for (int nt = 0; nt < 4; ++nt) {
        float v = acc[mt][nt][r] * 0.125f * rn[nt];
        if (nt * 16 + l15 == row_i + 32) v = -5e4f;
        acc[mt][nt][r] = v;
        mx = fmaxf(mx, v);
      }
#pragma unroll
      for (int m = 8; m; m >>= 1) mx = fmaxf(mx, __shfl_xor(mx, m));
      float ssum = 0.f;
#pragma unroll
      for (int nt = 0; nt < 4; ++nt) {
        const float pe = expf(acc[mt][nt][r] - mx);
        ssum += pe;
        sP[w][row_i * 72 + nt * 16 + l15] = (f16)pe;
      }
#pragma unroll
      for (int m = 8; m; m >>= 1) ssum += __shfl_xor(ssum, m);
      pinv[mt][r] = 1.f / ssum;
    }
  __syncthreads();

  f32x4 pacc[2][4];
#pragma unroll
  for (int i = 0; i < 2; ++i)
#pragma unroll
    for (int j = 0; j < 4; ++j) pacc[i][j] = f32x4{0.f, 0.f, 0.f, 0.f};

#pragma unroll
  for (int kk = 0; kk < 2; ++kk) {
    f16x8 ap[2], bv[4];
#pragma unroll
    for (int mt = 0; mt < 2; ++mt)
      ap[mt] = *(const f16x8*)&sP[w][(mt * 16 + l15) * 72 + kk * 32 + l4 * 8];
#pragma unroll
    for (int nt = 0; nt < 4; ++nt)
      bv[nt] = *(const f16x8*)&sVT[(nt * 16 + l15) * 168 + w * 32 + kk * 32 + l4 * 8];
#pragma unroll
    for (int mt = 0; mt < 2; ++mt)
#pragma unroll
      for (int nt = 0; nt < 4; ++nt)
        pacc[mt][nt] = __builtin_amdgcn_mfma_f32_16x16x32_f16(ap[mt], bv[nt], pacc[mt][nt], 0, 0, 0);
  }

  const long ob = (long)b * 4096 * 512 + h * 64;
#pragma unroll
  for (int mt = 0; mt < 2; ++mt)
#pragma unroll
    for (int r = 0; r < 4; ++r) {
      const int row_i = mt * 16 + l4 * 4 + r;
      const long t = st[32 + w * 32 + row_i];
      const float sc = pinv[mt][r];
#pragma unroll
      for (int nt = 0; nt < 4; ++nt)
        o[ob + t * 512 + nt * 16 + l15] = (f16)(pacc[mt][nt][r] * sc);
    }
}

// ---------------------------------------------------------------------------
extern "C" void kernel_launch(void* const* d_in, const int* in_sizes, int n_in,
                              void* d_out, int out_size, void* d_ws, size_t ws_size,
                              hipStream_t stream)
{
  const float* x     = (const float*)d_in[0];
  const float* w_qk  = (const float*)d_in[1];
  const float* w_v   = (const float*)d_in[2];
  const float* w_out = (const float*)d_in[3];
  const float* b_out = (const float*)d_in[4];
  const float* ln1g  = (const float*)d_in[5];
  const float* ln1b  = (const float*)d_in[6];
  const float* w_ff1 = (const float*)d_in[7];
  const float* b_ff1 = (const float*)d_in[8];
  const float* w_ff2 = (const float*)d_in[9];
  const float* b_ff2 = (const float*)d_in[10];
  const float* ln2g  = (const float*)d_in[11];
  const float* ln2b  = (const float*)d_in[12];
  const float* rot   = (const float*)d_in[13];
  float* out = (float*)d_out;

  char* ws = (char*)d_ws;
  // [0,32M):  hh (ln1 out, dead after qkv) -> o_buf (attn2 out, dead after
  //           wout) -> h2 (ln16 out, dead after FFN1-chunk1)
  // [32,64M): xh (ln1 out) -> sxy (wout EPI12, in-place over xh; live to end)
  // [64,128M): gqk[64,96M)+gv[96,128M) (dead after attn2) -> y1h[64,96M)
  //            (wout out, dead after ln16) -> abuf[64,128M) (FFN mid)
  // [128M,+9.1M): weights + WrT + buckets + sticker + rotTh
  f16* hh     = (f16*)ws;
  f16* o_buf  = (f16*)ws;
  f16* h2     = (f16*)ws;
  f16* xh     = (f16*)(ws + 33554432);
  f16* sxy    = (f16*)(ws + 33554432);
  f16* gqk    = (f16*)(ws + 67108864);
  f16* gv     = (f16*)(ws + 100663296);
  f16* y1h    = (f16*)(ws + 67108864);
  f16* abuf   = (f16*)(ws + 67108864);
  char* W0 = ws + 134217728;
  f16* wqkvT = (f16*)W0;                        // [1024][512]
  f16* woutT = (f16*)(W0 + 1048576);            // [512][512]
  f16* wff1T = (f16*)(W0 + 1572864);            // [2048][512]
  f16* wff2T = (f16*)(W0 + 3670016);            // [512][2048]
  float* WrT = (float*)(W0 + 5767168);          // [512][512] fp32
  int* buckets = (int*)(W0 + 6815744);          // [64][4096]
  int* sticker = (int*)(W0 + 7864320);          // [64][4096]
  f16* rotTh   = (f16*)(W0 + 8912896);          // [64][64]

  const dim3 b256(256);
  const dim3 b512(512);
  transpose_f16<<<dim3(16, 16), b256, 0, stream>>>(w_qk,  wqkvT,             512, 512);
  transpose_f16<<<dim3(16, 16), b256, 0, stream>>>(w_v,   wqkvT + 512 * 512, 512, 512);
  transpose_f16<<<dim3(16, 16), b256, 0, stream>>>(w_out, woutT,             512, 512);
  transpose_f16<<<dim3(64, 16), b256, 0, stream>>>(w_ff1, wff1T,             512, 2048);
  transpose_f16<<<dim3(16, 64), b256, 0, stream>>>(w_ff2, wff2T,             2048, 512);
  whash_f32<<<dim3(512, 2), b256, 0, stream>>>(w_qk, rot, WrT, rotTh);
  // LN1: hh = f16 LN(x) (stride 512); xh = f16 x
  ln_x16_kernel<<<dim3(8192), b256, 0, stream>>>(x, ln1g, ln1b, hh, xh);
  // qkv = h1 @ [w_qk | w_v], head-major f16 out (8-phase 256^2)
  gemm256<17><<<dim3(4, 128), b512, 0, stream>>>(hh, 512, wqkvT, 512, 512, 1024,
      nullptr, gqk, gv, nullptr, nullptr);
  // approx hash (no atomics) + exact fixup (recomputes LN from x) + sort + attn
  rhash4_kernel<<<dim3(2048), b256, 0, stream>>>(gqk, rotTh, buckets);
  fixup2_kernel<<<dim3(256), b256, 0, stream>>>(x, ln1g, ln1b, WrT, buckets);
  sort_kernel<<<dim3(64), b256, 0, stream>>>(buckets, sticker);
  attn2_kernel<<<dim3(32, 64), b256, 0, stream>>>(gqk, gv, sticker, o_buf);
  // wout: y1h = xh + o @ w_out + b_out;  sxy = xh + 0.5*(c+bias) (in-place)
  gemm256<12><<<dim3(2, 128), b512, 0, stream>>>(o_buf, 512, woutT, 512, 512, 512,
      nullptr, sxy, y1h, b_out, xh);
  // ln2: h2 = LN(y1h)  (f16 input)
  ln16_kernel<<<dim3(8192), b256, 0, stream>>>(y1h, ln2g, ln2b, h2);
  // FFN in 2 row-chunks of 16384 (abuf = [16384][2048] = 64MB)
  for (int c = 0; c < 2; ++c) {
    const long roff = (long)c * 16384;
    gemm256<13><<<dim3(8, 64), b512, 0, stream>>>(h2 + roff * 512, 512, wff1T, 512,
        512, 2048, nullptr, abuf, nullptr, b_ff1, nullptr);
    ffn2_8ph<<<dim3(4, 64), b512, 0, stream>>>(abuf, wff2T, sxy + roff * 512,
        b_ff2, out + roff * 512);
  }
}

// Round 16
// 430.112 us; speedup vs baseline: 1.0244x; 1.0244x over previous
//
#include <hip/hip_runtime.h>
#include <stdint.h>

typedef _Float16 f16;
typedef _Float16 f16x8 __attribute__((ext_vector_type(8)));
typedef float    f32x4 __attribute__((ext_vector_type(4)));
typedef unsigned long long u64;

__device__ __forceinline__ void gload16(const void* g, void* l) {
  __builtin_amdgcn_global_load_lds(
      (__attribute__((address_space(1))) void*)g,
      (__attribute__((address_space(3))) void*)l, 16, 0, 0);
}

#define PH_PRE() \
  __builtin_amdgcn_s_barrier(); \
  asm volatile("s_waitcnt lgkmcnt(0)" ::: "memory"); \
  __builtin_amdgcn_sched_barrier(0); \
  __builtin_amdgcn_s_setprio(1);

#define PH_POST() \
  __builtin_amdgcn_s_setprio(0); \
  __builtin_amdgcn_s_barrier(); \
  __builtin_amdgcn_sched_barrier(0);

// ---------------------------------------------------------------------------
// 256x256-tile 8-phase GEMM (proven). 8 waves, 512 thr, 128KB LDS.
// EPI: 12 = f16 y1=c+bias+xh (->outh2) AND f16 sxy=xh+0.5(c+bias) (->outh,
//      in-place over xh) | 13 = f16 relu(c+bias) | 17 = qkv head-major
// ---------------------------------------------------------------------------
#define MFMA_QUAD(q, af) \
  _Pragma("unroll") for (int m2 = 0; m2 < 2; ++m2) \
  _Pragma("unroll") for (int nt = 0; nt < 4; ++nt) \
  _Pragma("unroll") for (int kk = 0; kk < 2; ++kk) \
    acc[(q)*2 + m2][nt] = __builtin_amdgcn_mfma_f32_16x16x32_f16( \
        af[m2][kk], bf[nt][kk], acc[(q)*2 + m2][nt], 0, 0, 0);

#define RD_A(dst, abase, q2) \
  _Pragma("unroll") for (int m2 = 0; m2 < 2; ++m2) \
  _Pragma("unroll") for (int kk = 0; kk < 2; ++kk) { \
    const int lr = (q2)*32 + m2*16 + l15; \
    dst[m2][kk] = *(const f16x8*)&abase[lr*64 + (((kk*4 + l4) ^ (lr & 7)) << 3)]; }

#define RD_B(bbase) \
  _Pragma("unroll") for (int nt = 0; nt < 4; ++nt) \
  _Pragma("unroll") for (int kk = 0; kk < 2; ++kk) { \
    const int lr = brow + nt*16 + l15; \
    bf[nt][kk] = *(const f16x8*)&bbase[lr*64 + (((kk*4 + l4) ^ (lr & 7)) << 3)]; }

template<int EPI>
__global__ __launch_bounds__(512, 2)
void gemm256(const f16* __restrict__ A, int lda,
             const f16* __restrict__ Bt, int ldb,
             int K, int N,
             float* __restrict__ outf, f16* __restrict__ outh,
             f16* __restrict__ outh2,
             const float* __restrict__ bias,
             const f16* __restrict__ xh)
{
  __shared__ __align__(16) f16 lds[65536];   // 128 KiB
  const int tid = threadIdx.x, lane = tid & 63;
  const int wid = tid >> 6;
  const int wm = wid >> 2, wn = wid & 3;
  const int l15 = lane & 15, l4 = lane >> 4;

  const int gx = gridDim.x;
  int lid = blockIdx.y * gx + blockIdx.x;
  const int cpx = (gx * gridDim.y) >> 3;
  lid = (lid & 7) * cpx + (lid >> 3);
  const long bm0 = (long)(lid / gx) * 256;
  const long bn0 = (long)(lid % gx) * 256;

  const int rs = tid >> 3, cs = tid & 7;
  const int cg = cs ^ (rs & 7);
  const int nkt = K >> 6;                    // pow2, >= 8
  const int nmask = nkt - 1;

  auto stageA = [&](int d, int half, int kt) {
    f16* dst = &lds[(d * 4 + half) * 8192];
    const long kb = (long)kt * 64 + cg * 8;
    const f16* src = A + (bm0 + half * 128) * lda + kb;
#pragma unroll
    for (int rr = 0; rr < 2; ++rr) {
      const int row = rs + rr * 64;
      gload16(src + (long)row * lda, dst + row * 64 + cs * 8);
    }
  };
  auto stageB = [&](int d, int half, int kt) {
    f16* dst = &lds[(d * 4 + 2 + half) * 8192];
    const long kb = (long)kt * 64 + cg * 8;
    const f16* src = Bt + (bn0 + half * 128) * ldb + kb;
#pragma unroll
    for (int rr = 0; rr < 2; ++rr) {
      const int row = rs + rr * 64;
      gload16(src + (long)row * ldb, dst + row * 64 + cs * 8);
    }
  };

  const f16* aBase0 = &lds[(0 + wm) * 8192];
  const f16* aBase1 = &lds[(4 + wm) * 8192];
  const f16* bBase0 = &lds[(2 + (wn >> 1)) * 8192];
  const f16* bBase1 = &lds[(6 + (wn >> 1)) * 8192];
  const int brow = (wn & 1) * 64;

  f32x4 acc[8][4];
#pragma unroll
  for (int i = 0; i < 8; ++i)
#pragma unroll
    for (int j = 0; j < 4; ++j) acc[i][j] = f32x4{0.f, 0.f, 0.f, 0.f};
  f16x8 bf[4][2], afA[2][2], afB[2][2];

  stageB(0, 0, 0); stageB(0, 1, 0); stageA(0, 0, 0); stageA(0, 1, 0);
  asm volatile("s_waitcnt vmcnt(4)" ::: "memory");
  stageB(1, 0, 1); stageB(1, 1, 1); stageA(1, 0, 1);
  asm volatile("s_waitcnt vmcnt(6)" ::: "memory");
  __builtin_amdgcn_s_barrier();
  __builtin_amdgcn_sched_barrier(0);

  for (int j = 0; j < nkt; j += 2) {
    const int t2 = (j + 2) & nmask, t3 = (j + 3) & nmask;
    RD_B(bBase0); RD_A(afA, aBase0, 0);
    stageA(1, 1, (j + 1) & nmask);
    asm volatile("s_waitcnt lgkmcnt(8)" ::: "memory");
    PH_PRE(); MFMA_QUAD(0, afA); PH_POST();
    RD_A(afB, aBase0, 1); RD_A(afA, aBase0, 2);
    stageB(0, 0, t2);
    PH_PRE(); MFMA_QUAD(1, afB); PH_POST();
    RD_A(afB, aBase0, 3);
    stageB(0, 1, t2);
    PH_PRE(); MFMA_QUAD(2, afA); PH_POST();
    stageA(0, 0, t2);
    asm volatile("s_waitcnt vmcnt(6)" ::: "memory");
    PH_PRE(); MFMA_QUAD(3, afB); PH_POST();
    RD_B(bBase1); RD_A(afA, aBase1, 0);
    stageA(0, 1, t2);
    asm volatile("s_waitcnt lgkmcnt(8)" ::: "memory");
    PH_PRE(); MFMA_QUAD(0, afA); PH_POST();
    RD_A(afB, aBase1, 1); RD_A(afA, aBase1, 2);
    stageB(1, 0, t3);
    PH_PRE(); MFMA_QUAD(1, afB); PH_POST();
    RD_A(afB, aBase1, 3);
    stageB(1, 1, t3);
    PH_PRE(); MFMA_QUAD(2, afA); PH_POST();
    stageA(1, 0, t3);
    asm volatile("s_waitcnt vmcnt(6)" ::: "memory");
    PH_PRE(); MFMA_QUAD(3, afB); PH_POST();
  }
  asm volatile("s_waitcnt vmcnt(0)" ::: "memory");

#pragma unroll
  for (int mt = 0; mt < 8; ++mt)
#pragma unroll
    for (int nt = 0; nt < 4; ++nt)
#pragma unroll
      for (int r = 0; r < 4; ++r) {
        const long grow = bm0 + wm * 128 + mt * 16 + l4 * 4 + r;
        const long gcol = bn0 + wn * 64 + nt * 16 + l15;
        const float c = acc[mt][nt][r];
        if constexpr (EPI == 12) {
          const long idx = grow * (long)N + gcol;
          const float t = c + bias[gcol];
          const float xx = (float)xh[idx];
          outh2[idx] = (f16)(t + xx);         // y1 (f16)
          outh[idx]  = (f16)(xx + 0.5f * t);  // sxy = 0.5*(x+y1), in-place
        } else if constexpr (EPI == 13) {
          const long idx = grow * (long)N + gcol;
          outh[idx] = (f16)fmaxf(c + bias[gcol], 0.f);
        } else if constexpr (EPI == 17) {
          const int bb = (int)(grow >> 12), tt = (int)(grow & 4095);
          const int hcol = (int)(bn0 >> 6) + wn;
          const int is_v = hcol >> 3, h = hcol & 7;
          f16* base = is_v ? outh2 : outh;
          base[(((long)bb * 8 + h) * 4096 + tt) * 64 + nt * 16 + l15] = (f16)c;
        }
      }
}

// ---------------------------------------------------------------------------
// FFN2 8-phase GEMM (proven): BM=256 x BN=128, BK=64, K=2048, 8 waves,
// 96KB LDS. out = sxy + 0.5*(c + bias).
// ---------------------------------------------------------------------------
#define RD2_B(bbase) \
  _Pragma("unroll") for (int nt = 0; nt < 4; ++nt) \
  _Pragma("unroll") for (int kk = 0; kk < 2; ++kk) { \
    const int lr = brow + nt*16 + l15; \
    bf[nt][kk] = *(const f16x8*)&bbase[lr*64 + (((kk*4 + l4) ^ (lr & 7)) << 3)]; }

#define RD2_A(dst, abase, mt) \
  _Pragma("unroll") for (int kk = 0; kk < 2; ++kk) { \
    const int lr = arow + (mt)*16 + l15; \
    dst[kk] = *(const f16x8*)&abase[lr*64 + (((kk*4 + l4) ^ (lr & 7)) << 3)]; }

#define MFMA_Q1(mt, af) \
  _Pragma("unroll") for (int nt = 0; nt < 4; ++nt) \
  _Pragma("unroll") for (int kk = 0; kk < 2; ++kk) \
    acc[mt][nt] = __builtin_amdgcn_mfma_f32_16x16x32_f16( \
        af[kk], bf[nt][kk], acc[mt][nt], 0, 0, 0);

__global__ __launch_bounds__(512, 2)
void ffn2_8ph(const f16* __restrict__ A, const f16* __restrict__ Bt,
              const f16* __restrict__ sxyh, const float* __restrict__ bias,
              float* __restrict__ outf)
{
  __shared__ __align__(16) f16 lds[49152];   // 96 KiB: 6 x 16KB regions
  const int tid = threadIdx.x, lane = tid & 63;
  const int wid = tid >> 6;
  const int wm = wid >> 1, wn = wid & 1;     // 4M x 2N
  const int l15 = lane & 15, l4 = lane >> 4;

  const int gx = gridDim.x;                  // 4
  int lid = blockIdx.y * gx + blockIdx.x;
  const int cpx = (gx * gridDim.y) >> 3;
  lid = (lid & 7) * cpx + (lid >> 3);
  const long bm0 = (long)(lid / gx) * 256;
  const long bn0 = (long)(lid % gx) * 128;

  const int rs = tid >> 3, cs = tid & 7;
  const int cg = cs ^ (rs & 7);
  const int nmask = 31;                      // nkt = 32

  auto stageA = [&](int d, int half, int kt) {
    f16* dst = &lds[(d * 3 + half) * 8192];
    const long kb = (long)kt * 64 + cg * 8;
    const f16* src = A + (bm0 + half * 128) * 2048 + kb;
#pragma unroll
    for (int rr = 0; rr < 2; ++rr) {
      const int row = rs + rr * 64;
      gload16(src + (long)row * 2048, dst + row * 64 + cs * 8);
    }
  };
  auto stageB = [&](int d, int kt) {
    f16* dst = &lds[(d * 3 + 2) * 8192];
    const long kb = (long)kt * 64 + cg * 8;
    const f16* src = Bt + bn0 * 2048 + kb;
#pragma unroll
    for (int rr = 0; rr < 2; ++rr) {
      const int row = rs + rr * 64;
      gload16(src + (long)row * 2048, dst + row * 64 + cs * 8);
    }
  };

  const f16* aBase0 = &lds[(0 + (wm >> 1)) * 8192];
  const f16* aBase1 = &lds[(3 + (wm >> 1)) * 8192];
  const f16* bBase0 = &lds[2 * 8192];
  const f16* bBase1 = &lds[5 * 8192];
  const int arow = (wm & 1) * 64;
  const int brow = wn * 64;

  f32x4 acc[4][4];
#pragma unroll
  for (int i = 0; i < 4; ++i)
#pragma unroll
    for (int j = 0; j < 4; ++j) acc[i][j] = f32x4{0.f, 0.f, 0.f, 0.f};
  f16x8 bf[4][2], afA[2], afB[2];

  // prologue: t0 full, t1 full; wait t0
  stageB(0, 0); stageA(0, 0, 0); stageA(0, 1, 0);
  stageB(1, 1); stageA(1, 0, 1); stageA(1, 1, 1);
  asm volatile("s_waitcnt vmcnt(6)" ::: "memory");
  __builtin_amdgcn_s_barrier();
  __builtin_amdgcn_sched_barrier(0);

  for (int j = 0; j < 32; j += 2) {
    const int t2 = (j + 2) & nmask, t3 = (j + 3) & nmask;
    // ---- tile j (buf0) ----
    RD2_B(bBase0); RD2_A(afA, aBase0, 0);
    asm volatile("s_waitcnt lgkmcnt(8)" ::: "memory");
    PH_PRE(); MFMA_Q1(0, afA); PH_POST();
    RD2_A(afB, aBase0, 1); RD2_A(afA, aBase0, 2);
    stageB(0, t2);
    PH_PRE(); MFMA_Q1(1, afB); PH_POST();
    RD2_A(afB, aBase0, 3);
    PH_PRE(); MFMA_Q1(2, afA); PH_POST();
    stageA(0, 0, t2); stageA(0, 1, t2);
    asm volatile("s_waitcnt vmcnt(6)" ::: "memory");
    PH_PRE(); MFMA_Q1(3, afB); PH_POST();
    // ---- tile j+1 (buf1) ----
    RD2_B(bBase1); RD2_A(afA, aBase1, 0);
    asm volatile("s_waitcnt lgkmcnt(8)" ::: "memory");
    PH_PRE(); MFMA_Q1(0, afA); PH_POST();
    RD2_A(afB, aBase1, 1); RD2_A(afA, aBase1, 2);
    stageB(1, t3);
    PH_PRE(); MFMA_Q1(1, afB); PH_POST();
    RD2_A(afB, aBase1, 3);
    PH_PRE(); MFMA_Q1(2, afA); PH_POST();
    stageA(1, 0, t3); stageA(1, 1, t3);
    asm volatile("s_waitcnt vmcnt(6)" ::: "memory");
    PH_PRE(); MFMA_Q1(3, afB); PH_POST();
  }
  asm volatile("s_waitcnt vmcnt(0)" ::: "memory");

#pragma unroll
  for (int mt = 0; mt < 4; ++mt)
#pragma unroll
    for (int nt = 0; nt < 4; ++nt)
#pragma unroll
      for (int r = 0; r < 4; ++r) {
        const long grow = bm0 + wm * 64 + mt * 16 + l4 * 4 + r;
        const long gcol = bn0 + wn * 64 + nt * 16 + l15;
        const long idx = grow * 512 + gcol;
        outf[idx] = (float)sxyh[idx] + 0.5f * (acc[mt][nt][r] + bias[gcol]);
      }
}

// ---------------------------------------------------------------------------
// LN1: reads fp32 x, writes hh = (f16)LN(x) (stride 512) AND xh = (f16)x.
// ---------------------------------------------------------------------------
__global__ __launch_bounds__(256)
void ln_x16_kernel(const float* __restrict__ in, const float* __restrict__ gam,
                   const float* __restrict__ bet, f16* __restrict__ hh,
                   f16* __restrict__ xh)
{
  const long row = (long)blockIdx.x * 4 + (threadIdx.x >> 6);
  const int lane = threadIdx.x & 63;
  const float4* p = (const float4*)(in + row * 512);
  const float4 a = p[lane * 2], b = p[lane * 2 + 1];
  float xv[8] = {a.x, a.y, a.z, a.w, b.x, b.y, b.z, b.w};
  float s = 0.f;
#pragma unroll
  for (int i = 0; i < 8; ++i) s += xv[i];
#pragma unroll
  for (int m = 32; m; m >>= 1) s += __shfl_xor(s, m);
  const float mean = s * (1.f / 512.f);
  float vs = 0.f;
#pragma unroll
  for (int i = 0; i < 8; ++i) { const float d = xv[i] - mean; vs += d * d; }
#pragma unroll
  for (int m = 32; m; m >>= 1) vs += __shfl_xor(vs, m);
  const float rstd = 1.f / sqrtf(vs * (1.f / 512.f) + 1e-5f);
  const float4* gp = (const float4*)gam;
  const float4* bp = (const float4*)bet;
  const float4 g0 = gp[lane * 2], g1 = gp[lane * 2 + 1];
  const float4 b0 = bp[lane * 2], b1 = bp[lane * 2 + 1];
  const float gg[8] = {g0.x, g0.y, g0.z, g0.w, g1.x, g1.y, g1.z, g1.w};
  const float bb[8] = {b0.x, b0.y, b0.z, b0.w, b1.x, b1.y, b1.z, b1.w};
  f16x8 vh, vx;
#pragma unroll
  for (int i = 0; i < 8; ++i) {
    vh[i] = (f16)((xv[i] - mean) * rstd * gg[i] + bb[i]);
    vx[i] = (f16)xv[i];
  }
  *(f16x8*)(hh + row * 512 + lane * 8) = vh;
  *(f16x8*)(xh + row * 512 + lane * 8) = vx;
}

// ---------------------------------------------------------------------------
// LN2 over D=512, f16 input (y1h), f16 output.
// ---------------------------------------------------------------------------
__global__ __launch_bounds__(256)
void ln16_kernel(const f16* __restrict__ in, const float* __restrict__ gam,
                 const float* __restrict__ bet, f16* __restrict__ out)
{
  const long row = (long)blockIdx.x * 4 + (threadIdx.x >> 6);
  const int lane = threadIdx.x & 63;
  const f16x8 v = *(const f16x8*)(in + row * 512 + lane * 8);
  float xv[8];
#pragma unroll
  for (int i = 0; i < 8; ++i) xv[i] = (float)v[i];
  float s = 0.f;
#pragma unroll
  for (int i = 0; i < 8; ++i) s += xv[i];
#pragma unroll
  for (int m = 32; m; m >>= 1) s += __shfl_xor(s, m);
  const float mean = s * (1.f / 512.f);
  float vs = 0.f;
#pragma unroll
  for (int i = 0; i < 8; ++i) { const float d = xv[i] - mean; vs += d * d; }
#pragma unroll
  for (int m = 32; m; m >>= 1) vs += __shfl_xor(vs, m);
  const float rstd = 1.f / sqrtf(vs * (1.f / 512.f) + 1e-5f);
  const float4* gp = (const float4*)gam;
  const float4* bp = (const float4*)bet;
  const float4 g0 = gp[lane * 2], g1 = gp[lane * 2 + 1];
  const float4 b0 = bp[lane * 2], b1 = bp[lane * 2 + 1];
  const float gg[8] = {g0.x, g0.y, g0.z, g0.w, g1.x, g1.y, g1.z, g1.w};
  const float bb[8] = {b0.x, b0.y, b0.z, b0.w, b1.x, b1.y, b1.z, b1.w};
  f16x8 vh;
#pragma unroll
  for (int i = 0; i < 8; ++i)
    vh[i] = (f16)((xv[i] - mean) * rstd * gg[i] + bb[i]);
  *(f16x8*)(out + row * 512 + lane * 8) = vh;
}

// ---------------------------------------------------------------------------
// Batched weight transpose: all 5 fp32 [K][N] -> f16 [N][K] jobs in one
// launch. Flat grid of 2816 blocks; ranges select the job.
// ---------------------------------------------------------------------------
__global__ __launch_bounds__(256)
void transpose_all(const float* __restrict__ w_qk, const float* __restrict__ w_v,
                   const float* __restrict__ w_out, const float* __restrict__ w_ff1,
                   const float* __restrict__ w_ff2,
                   f16* __restrict__ wqkvT, f16* __restrict__ woutT,
                   f16* __restrict__ wff1T, f16* __restrict__ wff2T)
{
  __shared__ float tile[32][33];
  const int bid = blockIdx.x;
  const float* src; f16* dst; int K, N, bx, by;
  if (bid < 256)       { src = w_qk;  dst = wqkvT;             K = 512;  N = 512;  int r = bid;        bx = r & 15; by = r >> 4; }
  else if (bid < 512)  { src = w_v;   dst = wqkvT + 512 * 512; K = 512;  N = 512;  int r = bid - 256;  bx = r & 15; by = r >> 4; }
  else if (bid < 768)  { src = w_out; dst = woutT;             K = 512;  N = 512;  int r = bid - 512;  bx = r & 15; by = r >> 4; }
  else if (bid < 1792) { src = w_ff1; dst = wff1T;             K = 512;  N = 2048; int r = bid - 768;  bx = r & 63; by = r >> 6; }
  else                 { src = w_ff2; dst = wff2T;             K = 2048; N = 512;  int r = bid - 1792; bx = r & 15; by = r >> 4; }
  const int tx = threadIdx.x & 31, ty = threadIdx.x >> 5;
  const long k0 = (long)by * 32, n0 = (long)bx * 32;
#pragma unroll
  for (int i = 0; i < 4; ++i)
    tile[ty + i * 8][tx] = src[(k0 + ty + i * 8) * N + n0 + tx];
  __syncthreads();
#pragma unroll
  for (int i = 0; i < 4; ++i)
    dst[(n0 + ty + i * 8) * K + k0 + tx] = (f16)tile[tx][ty + i * 8];
}

// ---------------------------------------------------------------------------
// WrT[n][k] fp32 (fixup) + rotTh f16 [i][d] (rhash).
// ---------------------------------------------------------------------------
__global__ __launch_bounds__(256)
void whash_f32(const float* __restrict__ wqk, const float* __restrict__ rot,
               float* __restrict__ WrT, f16* __restrict__ rotTh)
{
  if (blockIdx.x == 0 && blockIdx.y == 0) {
    for (int idx = threadIdx.x; idx < 4096; idx += 256) {
      const int d = idx >> 6, i = idx & 63;
      rotTh[i * 64 + d] = (f16)rot[idx];
    }
  }
  const int kk = blockIdx.x;                     // 0..511
  const int n  = blockIdx.y * 256 + threadIdx.x; // 0..511
  const int h = n >> 6, i = n & 63;
  float s = 0.f;
  for (int d = 0; d < 64; ++d)
    s += wqk[kk * 512 + h * 64 + d] * rot[d * 64 + i];
  WrT[(long)n * 512 + kk] = s;
}

// ---------------------------------------------------------------------------
// rhash4: r = qk . rot^T via MFMA (K=64). bucket = argmax over [r,-r].
// No atomics: packs bucket|col2<<8|col3<<16|flag<<24 into buckets.
// ---------------------------------------------------------------------------
__global__ __launch_bounds__(256)
void rhash4_kernel(const f16* __restrict__ gqk, const f16* __restrict__ rotTh,
                   int* __restrict__ buckets)
{
  const int tid = threadIdx.x, lane = tid & 63, w = tid >> 6;
  const int bh = blockIdx.x >> 5, tb = blockIdx.x & 31;
  const int t0 = tb * 128;
  const int l15 = lane & 15, l4 = lane >> 4;

  f16x8 br[2][4];
#pragma unroll
  for (int kk = 0; kk < 2; ++kk)
#pragma unroll
    for (int nt = 0; nt < 4; ++nt)
      br[kk][nt] = *(const f16x8*)&rotTh[(nt * 16 + l15) * 64 + kk * 32 + l4 * 8];

  const f16* gqb = gqk + ((long)bh * 4096 + t0) * 64;
  f16x8 aq[2][2];
#pragma unroll
  for (int kk = 0; kk < 2; ++kk)
#pragma unroll
    for (int mt = 0; mt < 2; ++mt)
      aq[kk][mt] = *(const f16x8*)&gqb[(long)(w * 32 + mt * 16 + l15) * 64 + kk * 32 + l4 * 8];

  f32x4 acc[2][4];
#pragma unroll
  for (int i = 0; i < 2; ++i)
#pragma unroll
    for (int j = 0; j < 4; ++j) acc[i][j] = f32x4{0.f, 0.f, 0.f, 0.f};
#pragma unroll
  for (int kk = 0; kk < 2; ++kk)
#pragma unroll
    for (int mt = 0; mt < 2; ++mt)
#pragma unroll
      for (int nt = 0; nt < 4; ++nt)
        acc[mt][nt] = __builtin_amdgcn_mfma_f32_16x16x32_f16(aq[kk][mt], br[kk][nt], acc[mt][nt], 0, 0, 0);

#pragma unroll
  for (int mt = 0; mt < 2; ++mt)
#pragma unroll
    for (int r = 0; r < 4; ++r) {
      const float v0 = acc[mt][0][r], v1 = acc[mt][1][r];
      const float v2 = acc[mt][2][r], v3 = acc[mt][3][r];
      unsigned int k0 = (__float_as_uint(fabsf(v0)) & ~63u) | (unsigned int)(63 - l15);
      unsigned int k1 = (__float_as_uint(fabsf(v1)) & ~63u) | (unsigned int)(47 - l15);
      unsigned int k2 = (__float_as_uint(fabsf(v2)) & ~63u) | (unsigned int)(31 - l15);
      unsigned int k3 = (__float_as_uint(fabsf(v3)) & ~63u) | (unsigned int)(15 - l15);
      float ss = v0 * v0 + v1 * v1 + v2 * v2 + v3 * v3;
#pragma unroll
      for (int m = 1; m < 16; m <<= 1) ss += __shfl_xor(ss, m);

      unsigned int mk = max(max(k0, k1), max(k2, k3));
#pragma unroll
      for (int m = 1; m < 16; m <<= 1) mk = max(mk, (unsigned int)__shfl_xor((int)mk, m));
      const unsigned int key1 = mk;
      const int col1 = 63 - (int)(key1 & 63u);
      const float m1f = __uint_as_float(key1 & ~63u);
      const int nt1 = col1 >> 4;
      const float vsel = (nt1 == 0) ? v0 : (nt1 == 1) ? v1 : (nt1 == 2) ? v2 : v3;
      const bool owner = (col1 & 15) == l15;
      const u64 bal = __ballot(owner && (vsel < 0.f));
      const int neg = (int)((bal >> (l4 * 16 + (col1 & 15))) & 1ull);
      const int bucket = col1 + (neg << 6);
      if (owner) {
        if (nt1 == 0) k0 = 0; else if (nt1 == 1) k1 = 0;
        else if (nt1 == 2) k2 = 0; else k3 = 0;
      }
      mk = max(max(k0, k1), max(k2, k3));
#pragma unroll
      for (int m = 1; m < 16; m <<= 1) mk = max(mk, (unsigned int)__shfl_xor((int)mk, m));
      const int col2 = 63 - (int)(mk & 63u);
      const float m2f = __uint_as_float(mk & ~63u);
      {
        const int nt2 = col2 >> 4;
        if ((col2 & 15) == l15) {
          if (nt2 == 0) k0 = 0; else if (nt2 == 1) k1 = 0;
          else if (nt2 == 2) k2 = 0; else k3 = 0;
        }
      }
      mk = max(max(k0, k1), max(k2, k3));
#pragma unroll
      for (int m = 1; m < 16; m <<= 1) mk = max(mk, (unsigned int)__shfl_xor((int)mk, m));
      const int col3 = 63 - (int)(mk & 63u);

      if (l15 == 0) {
        const int row = w * 32 + mt * 16 + l4 * 4 + r;
        const int bht = bh * 4096 + t0 + row;
        const float margin = m1f - m2f;
        const float rms = sqrtf(ss * (1.f / 64.f));
        const int flag = (margin < 0.015f * rms) ? 1 : 0;
        buckets[bht] = bucket | (col2 << 8) | (col3 << 16) | (flag << 24);
      }
    }
}

// ---------------------------------------------------------------------------
// fixup2: scan flag bit; per-wave ballot compaction; exact fp32 re-eval.
// h1 recomputed as exact fp32 LN(x) per flagged row.
// ---------------------------------------------------------------------------
__global__ __launch_bounds__(256)
void fixup2_kernel(const float* __restrict__ x, const float* __restrict__ gam,
                   const float* __restrict__ bet, const float* __restrict__ WrT,
                   int* __restrict__ buckets)
{
  const int wid = (blockIdx.x * 256 + threadIdx.x) >> 6;   // 0..1023
  const int lane = threadIdx.x & 63;
  for (int batch = 0; batch < 4; ++batch) {
    const int base = wid * 256 + batch * 64;
    const int packed = buckets[base + lane];
    u64 bal = __ballot((packed >> 24) & 1);
    while (bal) {
      const int i = (int)__ffsll((long long)bal) - 1;
      bal &= bal - 1;
      const int row = base + i;
      const int pk = __shfl(packed, i);
      const int h = (row >> 12) & 7;
      const long hrow = (long)(row >> 15) * 4096 + (row & 4095);
      const float4* xp = (const float4*)(x + hrow * 512 + lane * 8);
      const float4 a = xp[0], b = xp[1];
      float xv[8] = {a.x, a.y, a.z, a.w, b.x, b.y, b.z, b.w};
      float s = 0.f;
#pragma unroll
      for (int k = 0; k < 8; ++k) s += xv[k];
#pragma unroll
      for (int m = 32; m; m >>= 1) s += __shfl_xor(s, m);
      const float mean = s * (1.f / 512.f);
      float vs = 0.f;
#pragma unroll
      for (int k = 0; k < 8; ++k) { const float d = xv[k] - mean; vs += d * d; }
#pragma unroll
      for (int m = 32; m; m >>= 1) vs += __shfl_xor(vs, m);
      const float rstd = 1.f / sqrtf(vs * (1.f / 512.f) + 1e-5f);
      const float4* gp = (const float4*)(gam + lane * 8);
      const float4* bp = (const float4*)(bet + lane * 8);
      const float4 g0 = gp[0], g1 = gp[1];
      const float4 bb0 = bp[0], bb1 = bp[1];
      const float gg[8] = {g0.x, g0.y, g0.z, g0.w, g1.x, g1.y, g1.z, g1.w};
      const float bb[8] = {bb0.x, bb0.y, bb0.z, bb0.w, bb1.x, bb1.y, bb1.z, bb1.w};
      float h1[8];
#pragma unroll
      for (int k = 0; k < 8; ++k) h1[k] = (xv[k] - mean) * rstd * gg[k] + bb[k];
      const int cols[3] = { pk & 63, (pk >> 8) & 63, (pk >> 16) & 63 };
      float best = -1e30f; int bi = 999;
#pragma unroll
      for (int c = 0; c < 3; ++c) {
        const int cc = cols[c];
        const float* wp = WrT + ((long)(h * 64 + cc)) * 512 + lane * 8;
        const float4 w0 = *(const float4*)wp;
        const float4 w1 = *(const float4*)(wp + 4);
        float sdot = h1[0] * w0.x + h1[1] * w0.y + h1[2] * w0.z + h1[3] * w0.w
                   + h1[4] * w1.x + h1[5] * w1.y + h1[6] * w1.z + h1[7] * w1.w;
#pragma unroll
        for (int m = 32; m; m >>= 1) sdot += __shfl_xor(sdot, m);
        if (sdot > best || (sdot == best && cc < bi)) { best = sdot; bi = cc; }
        const float ns = -sdot; const int ni = 64 + cc;
        if (ns > best || (ns == best && ni < bi)) { best = ns; bi = ni; }
      }
      if (lane == 0) buckets[row] = bi;
    }
  }
}

// ---------------------------------------------------------------------------
// Stable counting sort by (bucket, t) per bh. sticker[pos] = original t.
// ---------------------------------------------------------------------------
__global__ __launch_bounds__(256)
void sort_kernel(const int* __restrict__ buckets, int* __restrict__ sticker)
{
  __shared__ int bkt[4096];
  __shared__ unsigned int cnts[64][128];
  __shared__ unsigned char rnk[4096];
  __shared__ int tot[128];
  __shared__ int base[128];
  const int bh = blockIdx.x;
  const int tid = threadIdx.x;
  const int lane = tid & 63, wv = tid >> 6;

  for (int i = tid; i < 4096; i += 256) bkt[i] = buckets[(long)bh * 4096 + i] & 127;
  for (int i = tid; i < 64 * 128; i += 256) ((unsigned int*)cnts)[i] = 0u;
  __syncthreads();

  for (int it = 0; it < 16; ++it) {
    const int c = wv * 16 + it;
    const int t = c * 64 + lane;
    const int b = bkt[t];
    unsigned long long m = ~0ull;
#pragma unroll
    for (int k = 0; k < 7; ++k) {
      const bool bit = (b >> k) & 1;
      const unsigned long long bal = __ballot(bit);
      m &= bit ? bal : ~bal;
    }
    const int rk = (int)__popcll(m & ((1ull << lane) - 1ull));
    rnk[t] = (unsigned char)rk;
    if (rk == 0) cnts[c][b] = (unsigned int)__popcll(m);
  }
  __syncthreads();

  if (tid < 128) {
    unsigned int run = 0;
    for (int c = 0; c < 64; ++c) {
      const unsigned int x = cnts[c][tid];
      cnts[c][tid] = run;
      run += x;
    }
    tot[tid] = (int)run;
  }
  __syncthreads();
  if (tid == 0) {
    int run = 0;
    for (int b = 0; b < 128; ++b) { base[b] = run; run += tot[b]; }
  }
  __syncthreads();

  for (int it = 0; it < 16; ++it) {
    const int c = wv * 16 + it;
    const int t = c * 64 + lane;
    const int b = bkt[t];
    const int pos = base[b] + (int)cnts[c][b] + (int)rnk[t];
    sticker[(long)bh * 4096 + pos] = t;
  }
}

// ---------------------------------------------------------------------------
// LSH attention, gather version. Block = 256 thr / 4 waves / 4 chunks.
// ---------------------------------------------------------------------------
__global__ __launch_bounds__(256)
void attn2_kernel(const f16* __restrict__ gqk, const f16* __restrict__ gv,
                  const int* __restrict__ sticker, f16* __restrict__ o)
{
  __shared__ __align__(16) f16 sqk[160 * 64];     // granule-XOR swizzled
  __shared__ __align__(16) f16 sVT[64 * 168];     // [d][key 0..159]
  __shared__ __align__(16) f16 sP[4][32 * 72];
  __shared__ float rnorm[160];
  __shared__ int st[160];

  const int tid = threadIdx.x, lane = tid & 63, w = tid >> 6;
  const int cg = blockIdx.x, bh = blockIdx.y;
  const int b = bh >> 3, h = bh & 7;
  const int p0 = cg * 128 - 32;
  const int l15 = lane & 15, l4 = lane >> 4;

  if (tid < 160) st[tid] = sticker[(long)bh * 4096 + ((p0 + tid) & 4095)] & 4095;
  __syncthreads();

  const f16* gqb = gqk + (long)bh * 4096 * 64;
#pragma unroll
  for (int it = 0; it < 5; ++it) {
    const int idx = it * 256 + tid;
    const int row = idx >> 3, ch = idx & 7;
    const int gsrc = ch ^ (row & 7);
    gload16(gqb + (long)st[row] * 64 + gsrc * 8, &sqk[idx * 8]);
  }

  const f16* gvb = gv + (long)bh * 4096 * 64;
  f16x8 va[5];
#pragma unroll
  for (int i = 0; i < 5; ++i) {
    const int row = w * 40 + i * 8 + (lane >> 3);
    va[i] = *(const f16x8*)&gvb[(long)st[row] * 64 + (lane & 7) * 8];
  }
#pragma unroll
  for (int i = 0; i < 5; ++i) {
    const int row = w * 40 + i * 8 + (lane >> 3);
    const int d0 = (lane & 7) * 8;
#pragma unroll
    for (int e = 0; e < 8; ++e) sVT[(d0 + e) * 168 + row] = va[i][e];
  }
  __syncthreads();

  if (tid < 160) {
    float s = 0.f;
#pragma unroll
    for (int g = 0; g < 8; ++g) {
      const f16x8 v = *(const f16x8*)&sqk[tid * 64 + ((g ^ (tid & 7)) << 3)];
#pragma unroll
      for (int e = 0; e < 8; ++e) { const float f = (float)v[e]; s += f * f; }
    }
    rnorm[tid] = 1.f / fmaxf(sqrtf(s), 1e-12f);
  }
  __syncthreads();

  f32x4 acc[2][4];
#pragma unroll
  for (int i = 0; i < 2; ++i)
#pragma unroll
    for (int j = 0; j < 4; ++j) acc[i][j] = f32x4{0.f, 0.f, 0.f, 0.f};

#pragma unroll
  for (int kk = 0; kk < 2; ++kk) {
    f16x8 aq[2], bk[4];
#pragma unroll
    for (int mt = 0; mt < 2; ++mt) {
      const int row = 32 + w * 32 + mt * 16 + l15;
      const int g = kk * 4 + l4;
      aq[mt] = *(const f16x8*)&sqk[row * 64 + ((g ^ (row & 7)) << 3)];
    }
#pragma unroll
    for (int nt = 0; nt < 4; ++nt) {
      const int row = w * 32 + nt * 16 + l15;
      const int g = kk * 4 + l4;
      bk[nt] = *(const f16x8*)&sqk[row * 64 + ((g ^ (row & 7)) << 3)];
    }
#pragma unroll
    for (int mt = 0; mt < 2; ++mt)
#pragma unroll
      for (int nt = 0; nt < 4; ++nt)
        acc[mt][nt] = __builtin_amdgcn_mfma_f32_16x16x32_f16(aq[mt], bk[nt], acc[mt][nt], 0, 0, 0);
  }

  float rn[4];
#pragma unroll
  for (int nt = 0; nt < 4; ++nt) rn[nt] = rnorm[w * 32 + nt * 16 + l15];

  float pinv[2][4];
#pragma unroll
  for (int mt = 0; mt < 2; ++mt)
#pragma unroll
    for (int r = 0; r < 4; ++r) {
      const int row_i = mt * 16 + l4 * 4 + r;
      float mx = -1e30f;
#pragma unroll
      for (int nt = 0; nt < 4; ++nt) {
        float v = acc[mt][nt][r] * 0.125f * rn[nt];
        if (nt * 16 + l15 == row_i + 32) v = -5e4f;
        acc[mt][nt][r] = v;
        mx = fmaxf(mx, v);
      }
#pragma unroll
      for (int m = 8; m; m >>= 1) mx = fmaxf(mx, __shfl_xor(mx, m));
      float ssum = 0.f;
#pragma unroll
      for (int nt = 0; nt < 4; ++nt) {
        const float pe = expf(acc[mt][nt][r] - mx);
        ssum += pe;
        sP[w][row_i * 72 + nt * 16 + l15] = (f16)pe;
      }
#pragma unroll
      for (int m = 8; m; m >>= 1) ssum += __shfl_xor(ssum, m);
      pinv[mt][r] = 1.f / ssum;
    }
  __syncthreads();

  f32x4 pacc[2][4];
#pragma unroll
  for (int i = 0; i < 2; ++i)
#pragma unroll
    for (int j = 0; j < 4; ++j) pacc[i][j] = f32x4{0.f, 0.f, 0.f, 0.f};

#pragma unroll
  for (int kk = 0; kk < 2; ++kk) {
    f16x8 ap[2], bv[4];
#pragma unroll
    for (int mt = 0; mt < 2; ++mt)
      ap[mt] = *(const f16x8*)&sP[w][(mt * 16 + l15) * 72 + kk * 32 + l4 * 8];
#pragma unroll
    for (int nt = 0; nt < 4; ++nt)
      bv[nt] = *(const f16x8*)&sVT[(nt * 16 + l15) * 168 + w * 32 + kk * 32 + l4 * 8];
#pragma unroll
    for (int mt = 0; mt < 2; ++mt)
#pragma unroll
      for (int nt = 0; nt < 4; ++nt)
        pacc[mt][nt] = __builtin_amdgcn_mfma_f32_16x16x32_f16(ap[mt], bv[nt], pacc[mt][nt], 0, 0, 0);
  }

  const long ob = (long)b * 4096 * 512 + h * 64;
#pragma unroll
  for (int mt = 0; mt < 2; ++mt)
#pragma unroll
    for (int r = 0; r < 4; ++r) {
      const int row_i = mt * 16 + l4 * 4 + r;
      const long t = st[32 + w * 32 + row_i];
      const float sc = pinv[mt][r];
#pragma unroll
      for (int nt = 0; nt < 4; ++nt)
        o[ob + t * 512 + nt * 16 + l15] = (f16)(pacc[mt][nt][r] * sc);
    }
}

// ---------------------------------------------------------------------------
extern "C" void kernel_launch(void* const* d_in, const int* in_sizes, int n_in,
                              void* d_out, int out_size, void* d_ws, size_t ws_size,
                              hipStream_t stream)
{
  const float* x     = (const float*)d_in[0];
  const float* w_qk  = (const float*)d_in[1];
  const float* w_v   = (const float*)d_in[2];
  const float* w_out = (const float*)d_in[3];
  const float* b_out = (const float*)d_in[4];
  const float* ln1g  = (const float*)d_in[5];
  const float* ln1b  = (const float*)d_in[6];
  const float* w_ff1 = (const float*)d_in[7];
  const float* b_ff1 = (const float*)d_in[8];
  const float* w_ff2 = (const float*)d_in[9];
  const float* b_ff2 = (const float*)d_in[10];
  const float* ln2g  = (const float*)d_in[11];
  const float* ln2b  = (const float*)d_in[12];
  const float* rot   = (const float*)d_in[13];
  float* out = (float*)d_out;

  char* ws = (char*)d_ws;
  // [0,32M):  hh (ln1 out, dead after qkv) -> o_buf (attn2 out, dead after
  //           wout) -> h2 (ln16 out, dead after FFN1 chunks)
  // [32,64M): xh (ln1 out) -> sxy (wout EPI12, in-place over xh; live to end)
  // [64,128M): gqk[64,96M)+gv[96,128M) (dead after attn2) -> y1h[64,96M)
  //            (wout out, dead after ln16) -> abuf[64,128M) (FFN mid)
  // [128M,+9.1M): weights + WrT + buckets + sticker + rotTh
  f16* hh     = (f16*)ws;
  f16* o_buf  = (f16*)ws;
  f16* h2     = (f16*)ws;
  f16* xh     = (f16*)(ws + 33554432);
  f16* sxy    = (f16*)(ws + 33554432);
  f16* gqk    = (f16*)(ws + 67108864);
  f16* gv     = (f16*)(ws + 100663296);
  f16* y1h    = (f16*)(ws + 67108864);
  f16* abuf   = (f16*)(ws + 67108864);
  char* W0 = ws + 134217728;
  f16* wqkvT = (f16*)W0;                        // [1024][512]
  f16* woutT = (f16*)(W0 + 1048576);            // [512][512]
  f16* wff1T = (f16*)(W0 + 1572864);            // [2048][512]
  f16* wff2T = (f16*)(W0 + 3670016);            // [512][2048]
  float* WrT = (float*)(W0 + 5767168);          // [512][512] fp32
  int* buckets = (int*)(W0 + 6815744);          // [64][4096]
  int* sticker = (int*)(W0 + 7864320);          // [64][4096]
  f16* rotTh   = (f16*)(W0 + 8912896);          // [64][64]

  const dim3 b256(256);
  const dim3 b512(512);
  // all 5 weight transposes in one launch
  transpose_all<<<dim3(2816), b256, 0, stream>>>(w_qk, w_v, w_out, w_ff1, w_ff2,
      wqkvT, woutT, wff1T, wff2T);
  whash_f32<<<dim3(512, 2), b256, 0, stream>>>(w_qk, rot, WrT, rotTh);
  // LN1: hh = f16 LN(x) (stride 512); xh = f16 x
  ln_x16_kernel<<<dim3(8192), b256, 0, stream>>>(x, ln1g, ln1b, hh, xh);
  // qkv = h1 @ [w_qk | w_v], head-major f16 out (8-phase 256^2)
  gemm256<17><<<dim3(4, 128), b512, 0, stream>>>(hh, 512, wqkvT, 512, 512, 1024,
      nullptr, gqk, gv, nullptr, nullptr);
  // approx hash (no atomics) + exact fixup (recomputes LN from x) + sort + attn
  rhash4_kernel<<<dim3(2048), b256, 0, stream>>>(gqk, rotTh, buckets);
  fixup2_kernel<<<dim3(256), b256, 0, stream>>>(x, ln1g, ln1b, WrT, buckets);
  sort_kernel<<<dim3(64), b256, 0, stream>>>(buckets, sticker);
  attn2_kernel<<<dim3(32, 64), b256, 0, stream>>>(gqk, gv, sticker, o_buf);
  // wout: y1h = xh + o @ w_out + b_out;  sxy = xh + 0.5*(c+bias) (in-place)
  gemm256<12><<<dim3(2, 128), b512, 0, stream>>>(o_buf, 512, woutT, 512, 512, 512,
      nullptr, sxy, y1h, b_out, xh);
  // ln2: h2 = LN(y1h)  (f16 input)
  ln16_kernel<<<dim3(8192), b256, 0, stream>>>(y1h, ln2g, ln2b, h2);
  // FFN in 2 row-chunks of 16384 (abuf = [16384][2048] = 64MB)
  for (int c = 0; c < 2; ++c) {
    const long roff = (long)c * 16384;
    gemm256<13><<<dim3(8, 64), b512, 0, stream>>>(h2 + roff * 512, 512, wff1T, 512,
        512, 2048, nullptr, abuf, nullptr, b_ff1, nullptr);
    ffn2_8ph<<<dim3(4, 64), b512, 0, stream>>>(abuf, wff2T, sxy + roff * 512,
        b_ff2, out + roff * 512);
  }
}

// Round 17
// 427.982 us; speedup vs baseline: 1.0295x; 1.0050x over previous
//
#include <hip/hip_runtime.h>
#include <stdint.h>

typedef _Float16 f16;
typedef _Float16 f16x8 __attribute__((ext_vector_type(8)));
typedef float    f32x4 __attribute__((ext_vector_type(4)));
typedef unsigned long long u64;

__device__ __forceinline__ void gload16(const void* g, void* l) {
  __builtin_amdgcn_global_load_lds(
      (__attribute__((address_space(1))) void*)g,
      (__attribute__((address_space(3))) void*)l, 16, 0, 0);
}

#define PH_PRE() \
  __builtin_amdgcn_s_barrier(); \
  asm volatile("s_waitcnt lgkmcnt(0)" ::: "memory"); \
  __builtin_amdgcn_sched_barrier(0); \
  __builtin_amdgcn_s_setprio(1);

#define PH_POST() \
  __builtin_amdgcn_s_setprio(0); \
  __builtin_amdgcn_s_barrier(); \
  __builtin_amdgcn_sched_barrier(0);

// ---------------------------------------------------------------------------
// 256x256-tile 8-phase GEMM (proven). 8 waves, 512 thr, 128KB LDS.
// EPI: 12 = f16 y1=c+bias+xh (->outh2) AND f16 sxy=xh+0.5(c+bias) (->outh,
//      in-place over xh) | 13 = f16 relu(c+bias) | 17 = qkv head-major
// ---------------------------------------------------------------------------
#define MFMA_QUAD(q, af) \
  _Pragma("unroll") for (int m2 = 0; m2 < 2; ++m2) \
  _Pragma("unroll") for (int nt = 0; nt < 4; ++nt) \
  _Pragma("unroll") for (int kk = 0; kk < 2; ++kk) \
    acc[(q)*2 + m2][nt] = __builtin_amdgcn_mfma_f32_16x16x32_f16( \
        af[m2][kk], bf[nt][kk], acc[(q)*2 + m2][nt], 0, 0, 0);

#define RD_A(dst, abase, q2) \
  _Pragma("unroll") for (int m2 = 0; m2 < 2; ++m2) \
  _Pragma("unroll") for (int kk = 0; kk < 2; ++kk) { \
    const int lr = (q2)*32 + m2*16 + l15; \
    dst[m2][kk] = *(const f16x8*)&abase[lr*64 + (((kk*4 + l4) ^ (lr & 7)) << 3)]; }

#define RD_B(bbase) \
  _Pragma("unroll") for (int nt = 0; nt < 4; ++nt) \
  _Pragma("unroll") for (int kk = 0; kk < 2; ++kk) { \
    const int lr = brow + nt*16 + l15; \
    bf[nt][kk] = *(const f16x8*)&bbase[lr*64 + (((kk*4 + l4) ^ (lr & 7)) << 3)]; }

template<int EPI>
__global__ __launch_bounds__(512, 2)
void gemm256(const f16* __restrict__ A, int lda,
             const f16* __restrict__ Bt, int ldb,
             int K, int N,
             float* __restrict__ outf, f16* __restrict__ outh,
             f16* __restrict__ outh2,
             const float* __restrict__ bias,
             const f16* __restrict__ xh)
{
  __shared__ __align__(16) f16 lds[65536];   // 128 KiB
  const int tid = threadIdx.x, lane = tid & 63;
  const int wid = tid >> 6;
  const int wm = wid >> 2, wn = wid & 3;
  const int l15 = lane & 15, l4 = lane >> 4;

  const int gx = gridDim.x;
  int lid = blockIdx.y * gx + blockIdx.x;
  const int cpx = (gx * gridDim.y) >> 3;
  lid = (lid & 7) * cpx + (lid >> 3);
  const long bm0 = (long)(lid / gx) * 256;
  const long bn0 = (long)(lid % gx) * 256;

  const int rs = tid >> 3, cs = tid & 7;
  const int cg = cs ^ (rs & 7);
  const int nkt = K >> 6;                    // pow2, >= 8
  const int nmask = nkt - 1;

  auto stageA = [&](int d, int half, int kt) {
    f16* dst = &lds[(d * 4 + half) * 8192];
    const long kb = (long)kt * 64 + cg * 8;
    const f16* src = A + (bm0 + half * 128) * lda + kb;
#pragma unroll
    for (int rr = 0; rr < 2; ++rr) {
      const int row = rs + rr * 64;
      gload16(src + (long)row * lda, dst + row * 64 + cs * 8);
    }
  };
  auto stageB = [&](int d, int half, int kt) {
    f16* dst = &lds[(d * 4 + 2 + half) * 8192];
    const long kb = (long)kt * 64 + cg * 8;
    const f16* src = Bt + (bn0 + half * 128) * ldb + kb;
#pragma unroll
    for (int rr = 0; rr < 2; ++rr) {
      const int row = rs + rr * 64;
      gload16(src + (long)row * ldb, dst + row * 64 + cs * 8);
    }
  };

  const f16* aBase0 = &lds[(0 + wm) * 8192];
  const f16* aBase1 = &lds[(4 + wm) * 8192];
  const f16* bBase0 = &lds[(2 + (wn >> 1)) * 8192];
  const f16* bBase1 = &lds[(6 + (wn >> 1)) * 8192];
  const int brow = (wn & 1) * 64;

  f32x4 acc[8][4];
#pragma unroll
  for (int i = 0; i < 8; ++i)
#pragma unroll
    for (int j = 0; j < 4; ++j) acc[i][j] = f32x4{0.f, 0.f, 0.f, 0.f};
  f16x8 bf[4][2], afA[2][2], afB[2][2];

  stageB(0, 0, 0); stageB(0, 1, 0); stageA(0, 0, 0); stageA(0, 1, 0);
  asm volatile("s_waitcnt vmcnt(4)" ::: "memory");
  stageB(1, 0, 1); stageB(1, 1, 1); stageA(1, 0, 1);
  asm volatile("s_waitcnt vmcnt(6)" ::: "memory");
  __builtin_amdgcn_s_barrier();
  __builtin_amdgcn_sched_barrier(0);

  for (int j = 0; j < nkt; j += 2) {
    const int t2 = (j + 2) & nmask, t3 = (j + 3) & nmask;
    RD_B(bBase0); RD_A(afA, aBase0, 0);
    stageA(1, 1, (j + 1) & nmask);
    asm volatile("s_waitcnt lgkmcnt(8)" ::: "memory");
    PH_PRE(); MFMA_QUAD(0, afA); PH_POST();
    RD_A(afB, aBase0, 1); RD_A(afA, aBase0, 2);
    stageB(0, 0, t2);
    PH_PRE(); MFMA_QUAD(1, afB); PH_POST();
    RD_A(afB, aBase0, 3);
    stageB(0, 1, t2);
    PH_PRE(); MFMA_QUAD(2, afA); PH_POST();
    stageA(0, 0, t2);
    asm volatile("s_waitcnt vmcnt(6)" ::: "memory");
    PH_PRE(); MFMA_QUAD(3, afB); PH_POST();
    RD_B(bBase1); RD_A(afA, aBase1, 0);
    stageA(0, 1, t2);
    asm volatile("s_waitcnt lgkmcnt(8)" ::: "memory");
    PH_PRE(); MFMA_QUAD(0, afA); PH_POST();
    RD_A(afB, aBase1, 1); RD_A(afA, aBase1, 2);
    stageB(1, 0, t3);
    PH_PRE(); MFMA_QUAD(1, afB); PH_POST();
    RD_A(afB, aBase1, 3);
    stageB(1, 1, t3);
    PH_PRE(); MFMA_QUAD(2, afA); PH_POST();
    stageA(1, 0, t3);
    asm volatile("s_waitcnt vmcnt(6)" ::: "memory");
    PH_PRE(); MFMA_QUAD(3, afB); PH_POST();
  }
  asm volatile("s_waitcnt vmcnt(0)" ::: "memory");

#pragma unroll
  for (int mt = 0; mt < 8; ++mt)
#pragma unroll
    for (int nt = 0; nt < 4; ++nt)
#pragma unroll
      for (int r = 0; r < 4; ++r) {
        const long grow = bm0 + wm * 128 + mt * 16 + l4 * 4 + r;
        const long gcol = bn0 + wn * 64 + nt * 16 + l15;
        const float c = acc[mt][nt][r];
        if constexpr (EPI == 12) {
          const long idx = grow * (long)N + gcol;
          const float t = c + bias[gcol];
          const float xx = (float)xh[idx];
          outh2[idx] = (f16)(t + xx);         // y1 (f16)
          outh[idx]  = (f16)(xx + 0.5f * t);  // sxy = 0.5*(x+y1), in-place
        } else if constexpr (EPI == 13) {
          const long idx = grow * (long)N + gcol;
          outh[idx] = (f16)fmaxf(c + bias[gcol], 0.f);
        } else if constexpr (EPI == 17) {
          const int bb = (int)(grow >> 12), tt = (int)(grow & 4095);
          const int hcol = (int)(bn0 >> 6) + wn;
          const int is_v = hcol >> 3, h = hcol & 7;
          f16* base = is_v ? outh2 : outh;
          base[(((long)bb * 8 + h) * 4096 + tt) * 64 + nt * 16 + l15] = (f16)c;
        }
      }
}

// ---------------------------------------------------------------------------
// FFN2 8-phase GEMM (proven): BM=256 x BN=128, BK=64, K=2048, 8 waves,
// 96KB LDS. out = sxy + 0.5*(c + bias).
// ---------------------------------------------------------------------------
#define RD2_B(bbase) \
  _Pragma("unroll") for (int nt = 0; nt < 4; ++nt) \
  _Pragma("unroll") for (int kk = 0; kk < 2; ++kk) { \
    const int lr = brow + nt*16 + l15; \
    bf[nt][kk] = *(const f16x8*)&bbase[lr*64 + (((kk*4 + l4) ^ (lr & 7)) << 3)]; }

#define RD2_A(dst, abase, mt) \
  _Pragma("unroll") for (int kk = 0; kk < 2; ++kk) { \
    const int lr = arow + (mt)*16 + l15; \
    dst[kk] = *(const f16x8*)&abase[lr*64 + (((kk*4 + l4) ^ (lr & 7)) << 3)]; }

#define MFMA_Q1(mt, af) \
  _Pragma("unroll") for (int nt = 0; nt < 4; ++nt) \
  _Pragma("unroll") for (int kk = 0; kk < 2; ++kk) \
    acc[mt][nt] = __builtin_amdgcn_mfma_f32_16x16x32_f16( \
        af[kk], bf[nt][kk], acc[mt][nt], 0, 0, 0);

__global__ __launch_bounds__(512, 2)
void ffn2_8ph(const f16* __restrict__ A, const f16* __restrict__ Bt,
              const f16* __restrict__ sxyh, const float* __restrict__ bias,
              float* __restrict__ outf)
{
  __shared__ __align__(16) f16 lds[49152];   // 96 KiB: 6 x 16KB regions
  const int tid = threadIdx.x, lane = tid & 63;
  const int wid = tid >> 6;
  const int wm = wid >> 1, wn = wid & 1;     // 4M x 2N
  const int l15 = lane & 15, l4 = lane >> 4;

  const int gx = gridDim.x;                  // 4
  int lid = blockIdx.y * gx + blockIdx.x;
  const int cpx = (gx * gridDim.y) >> 3;
  lid = (lid & 7) * cpx + (lid >> 3);
  const long bm0 = (long)(lid / gx) * 256;
  const long bn0 = (long)(lid % gx) * 128;

  const int rs = tid >> 3, cs = tid & 7;
  const int cg = cs ^ (rs & 7);
  const int nmask = 31;                      // nkt = 32

  auto stageA = [&](int d, int half, int kt) {
    f16* dst = &lds[(d * 3 + half) * 8192];
    const long kb = (long)kt * 64 + cg * 8;
    const f16* src = A + (bm0 + half * 128) * 2048 + kb;
#pragma unroll
    for (int rr = 0; rr < 2; ++rr) {
      const int row = rs + rr * 64;
      gload16(src + (long)row * 2048, dst + row * 64 + cs * 8);
    }
  };
  auto stageB = [&](int d, int kt) {
    f16* dst = &lds[(d * 3 + 2) * 8192];
    const long kb = (long)kt * 64 + cg * 8;
    const f16* src = Bt + bn0 * 2048 + kb;
#pragma unroll
    for (int rr = 0; rr < 2; ++rr) {
      const int row = rs + rr * 64;
      gload16(src + (long)row * 2048, dst + row * 64 + cs * 8);
    }
  };

  const f16* aBase0 = &lds[(0 + (wm >> 1)) * 8192];
  const f16* aBase1 = &lds[(3 + (wm >> 1)) * 8192];
  const f16* bBase0 = &lds[2 * 8192];
  const f16* bBase1 = &lds[5 * 8192];
  const int arow = (wm & 1) * 64;
  const int brow = wn * 64;

  f32x4 acc[4][4];
#pragma unroll
  for (int i = 0; i < 4; ++i)
#pragma unroll
    for (int j = 0; j < 4; ++j) acc[i][j] = f32x4{0.f, 0.f, 0.f, 0.f};
  f16x8 bf[4][2], afA[2], afB[2];

  // prologue: t0 full, t1 full; wait t0
  stageB(0, 0); stageA(0, 0, 0); stageA(0, 1, 0);
  stageB(1, 1); stageA(1, 0, 1); stageA(1, 1, 1);
  asm volatile("s_waitcnt vmcnt(6)" ::: "memory");
  __builtin_amdgcn_s_barrier();
  __builtin_amdgcn_sched_barrier(0);

  for (int j = 0; j < 32; j += 2) {
    const int t2 = (j + 2) & nmask, t3 = (j + 3) & nmask;
    // ---- tile j (buf0) ----
    RD2_B(bBase0); RD2_A(afA, aBase0, 0);
    asm volatile("s_waitcnt lgkmcnt(8)" ::: "memory");
    PH_PRE(); MFMA_Q1(0, afA); PH_POST();
    RD2_A(afB, aBase0, 1); RD2_A(afA, aBase0, 2);
    stageB(0, t2);
    PH_PRE(); MFMA_Q1(1, afB); PH_POST();
    RD2_A(afB, aBase0, 3);
    PH_PRE(); MFMA_Q1(2, afA); PH_POST();
    stageA(0, 0, t2); stageA(0, 1, t2);
    asm volatile("s_waitcnt vmcnt(6)" ::: "memory");
    PH_PRE(); MFMA_Q1(3, afB); PH_POST();
    // ---- tile j+1 (buf1) ----
    RD2_B(bBase1); RD2_A(afA, aBase1, 0);
    asm volatile("s_waitcnt lgkmcnt(8)" ::: "memory");
    PH_PRE(); MFMA_Q1(0, afA); PH_POST();
    RD2_A(afB, aBase1, 1); RD2_A(afA, aBase1, 2);
    stageB(1, t3);
    PH_PRE(); MFMA_Q1(1, afB); PH_POST();
    RD2_A(afB, aBase1, 3);
    PH_PRE(); MFMA_Q1(2, afA); PH_POST();
    stageA(1, 0, t3); stageA(1, 1, t3);
    asm volatile("s_waitcnt vmcnt(6)" ::: "memory");
    PH_PRE(); MFMA_Q1(3, afB); PH_POST();
  }
  asm volatile("s_waitcnt vmcnt(0)" ::: "memory");

#pragma unroll
  for (int mt = 0; mt < 4; ++mt)
#pragma unroll
    for (int nt = 0; nt < 4; ++nt)
#pragma unroll
      for (int r = 0; r < 4; ++r) {
        const long grow = bm0 + wm * 64 + mt * 16 + l4 * 4 + r;
        const long gcol = bn0 + wn * 64 + nt * 16 + l15;
        const long idx = grow * 512 + gcol;
        outf[idx] = (float)sxyh[idx] + 0.5f * (acc[mt][nt][r] + bias[gcol]);
      }
}

// ---------------------------------------------------------------------------
// LN1: reads fp32 x, writes hh = (f16)LN(x) (stride 512) AND xh = (f16)x.
// ---------------------------------------------------------------------------
__global__ __launch_bounds__(256)
void ln_x16_kernel(const float* __restrict__ in, const float* __restrict__ gam,
                   const float* __restrict__ bet, f16* __restrict__ hh,
                   f16* __restrict__ xh)
{
  const long row = (long)blockIdx.x * 4 + (threadIdx.x >> 6);
  const int lane = threadIdx.x & 63;
  const float4* p = (const float4*)(in + row * 512);
  const float4 a = p[lane * 2], b = p[lane * 2 + 1];
  float xv[8] = {a.x, a.y, a.z, a.w, b.x, b.y, b.z, b.w};
  float s = 0.f;
#pragma unroll
  for (int i = 0; i < 8; ++i) s += xv[i];
#pragma unroll
  for (int m = 32; m; m >>= 1) s += __shfl_xor(s, m);
  const float mean = s * (1.f / 512.f);
  float vs = 0.f;
#pragma unroll
  for (int i = 0; i < 8; ++i) { const float d = xv[i] - mean; vs += d * d; }
#pragma unroll
  for (int m = 32; m; m >>= 1) vs += __shfl_xor(vs, m);
  const float rstd = 1.f / sqrtf(vs * (1.f / 512.f) + 1e-5f);
  const float4* gp = (const float4*)gam;
  const float4* bp = (const float4*)bet;
  const float4 g0 = gp[lane * 2], g1 = gp[lane * 2 + 1];
  const float4 b0 = bp[lane * 2], b1 = bp[lane * 2 + 1];
  const float gg[8] = {g0.x, g0.y, g0.z, g0.w, g1.x, g1.y, g1.z, g1.w};
  const float bb[8] = {b0.x, b0.y, b0.z, b0.w, b1.x, b1.y, b1.z, b1.w};
  f16x8 vh, vx;
#pragma unroll
  for (int i = 0; i < 8; ++i) {
    vh[i] = (f16)((xv[i] - mean) * rstd * gg[i] + bb[i]);
    vx[i] = (f16)xv[i];
  }
  *(f16x8*)(hh + row * 512 + lane * 8) = vh;
  *(f16x8*)(xh + row * 512 + lane * 8) = vx;
}

// ---------------------------------------------------------------------------
// LN2 over D=512, f16 input (y1h), f16 output.
// ---------------------------------------------------------------------------
__global__ __launch_bounds__(256)
void ln16_kernel(const f16* __restrict__ in, const float* __restrict__ gam,
                 const float* __restrict__ bet, f16* __restrict__ out)
{
  const long row = (long)blockIdx.x * 4 + (threadIdx.x >> 6);
  const int lane = threadIdx.x & 63;
  const f16x8 v = *(const f16x8*)(in + row * 512 + lane * 8);
  float xv[8];
#pragma unroll
  for (int i = 0; i < 8; ++i) xv[i] = (float)v[i];
  float s = 0.f;
#pragma unroll
  for (int i = 0; i < 8; ++i) s += xv[i];
#pragma unroll
  for (int m = 32; m; m >>= 1) s += __shfl_xor(s, m);
  const float mean = s * (1.f / 512.f);
  float vs = 0.f;
#pragma unroll
  for (int i = 0; i < 8; ++i) { const float d = xv[i] - mean; vs += d * d; }
#pragma unroll
  for (int m = 32; m; m >>= 1) vs += __shfl_xor(vs, m);
  const float rstd = 1.f / sqrtf(vs * (1.f / 512.f) + 1e-5f);
  const float4* gp = (const float4*)gam;
  const float4* bp = (const float4*)bet;
  const float4 g0 = gp[lane * 2], g1 = gp[lane * 2 + 1];
  const float4 b0 = bp[lane * 2], b1 = bp[lane * 2 + 1];
  const float gg[8] = {g0.x, g0.y, g0.z, g0.w, g1.x, g1.y, g1.z, g1.w};
  const float bb[8] = {b0.x, b0.y, b0.z, b0.w, b1.x, b1.y, b1.z, b1.w};
  f16x8 vh;
#pragma unroll
  for (int i = 0; i < 8; ++i)
    vh[i] = (f16)((xv[i] - mean) * rstd * gg[i] + bb[i]);
  *(f16x8*)(out + row * 512 + lane * 8) = vh;
}

// ---------------------------------------------------------------------------
// Batched weight transpose: all 5 fp32 [K][N] -> f16 [N][K] jobs in one
// launch. Flat grid of 2816 blocks; ranges select the job.
// ---------------------------------------------------------------------------
__global__ __launch_bounds__(256)
void transpose_all(const float* __restrict__ w_qk, const float* __restrict__ w_v,
                   const float* __restrict__ w_out, const float* __restrict__ w_ff1,
                   const float* __restrict__ w_ff2,
                   f16* __restrict__ wqkvT, f16* __restrict__ woutT,
                   f16* __restrict__ wff1T, f16* __restrict__ wff2T)
{
  __shared__ float tile[32][33];
  const int bid = blockIdx.x;
  const float* src; f16* dst; int K, N, bx, by;
  if (bid < 256)       { src = w_qk;  dst = wqkvT;             K = 512;  N = 512;  int r = bid;        bx = r & 15; by = r >> 4; }
  else if (bid < 512)  { src = w_v;   dst = wqkvT + 512 * 512; K = 512;  N = 512;  int r = bid - 256;  bx = r & 15; by = r >> 4; }
  else if (bid < 768)  { src = w_out; dst = woutT;             K = 512;  N = 512;  int r = bid - 512;  bx = r & 15; by = r >> 4; }
  else if (bid < 1792) { src = w_ff1; dst = wff1T;             K = 512;  N = 2048; int r = bid - 768;  bx = r & 63; by = r >> 6; }
  else                 { src = w_ff2; dst = wff2T;             K = 2048; N = 512;  int r = bid - 1792; bx = r & 15; by = r >> 4; }
  const int tx = threadIdx.x & 31, ty = threadIdx.x >> 5;
  const long k0 = (long)by * 32, n0 = (long)bx * 32;
#pragma unroll
  for (int i = 0; i < 4; ++i)
    tile[ty + i * 8][tx] = src[(k0 + ty + i * 8) * N + n0 + tx];
  __syncthreads();
#pragma unroll
  for (int i = 0; i < 4; ++i)
    dst[(n0 + ty + i * 8) * K + k0 + tx] = (f16)tile[tx][ty + i * 8];
}

// ---------------------------------------------------------------------------
// WrT[n][k] fp32 (fixup) + rotTh f16 [i][d] (rhash).
// ---------------------------------------------------------------------------
__global__ __launch_bounds__(256)
void whash_f32(const float* __restrict__ wqk, const float* __restrict__ rot,
               float* __restrict__ WrT, f16* __restrict__ rotTh)
{
  if (blockIdx.x == 0 && blockIdx.y == 0) {
    for (int idx = threadIdx.x; idx < 4096; idx += 256) {
      const int d = idx >> 6, i = idx & 63;
      rotTh[i * 64 + d] = (f16)rot[idx];
    }
  }
  const int kk = blockIdx.x;                     // 0..511
  const int n  = blockIdx.y * 256 + threadIdx.x; // 0..511
  const int h = n >> 6, i = n & 63;
  float s = 0.f;
  for (int d = 0; d < 64; ++d)
    s += wqk[kk * 512 + h * 64 + d] * rot[d * 64 + i];
  WrT[(long)n * 512 + kk] = s;
}

// ---------------------------------------------------------------------------
// rhash4: r = qk . rot^T via MFMA (K=64). bucket = argmax over [r,-r].
// No atomics: packs bucket|col2<<8|col3<<16|flag<<24 into buckets.
// ---------------------------------------------------------------------------
__global__ __launch_bounds__(256)
void rhash4_kernel(const f16* __restrict__ gqk, const f16* __restrict__ rotTh,
                   int* __restrict__ buckets)
{
  const int tid = threadIdx.x, lane = tid & 63, w = tid >> 6;
  const int bh = blockIdx.x >> 5, tb = blockIdx.x & 31;
  const int t0 = tb * 128;
  const int l15 = lane & 15, l4 = lane >> 4;

  f16x8 br[2][4];
#pragma unroll
  for (int kk = 0; kk < 2; ++kk)
#pragma unroll
    for (int nt = 0; nt < 4; ++nt)
      br[kk][nt] = *(const f16x8*)&rotTh[(nt * 16 + l15) * 64 + kk * 32 + l4 * 8];

  const f16* gqb = gqk + ((long)bh * 4096 + t0) * 64;
  f16x8 aq[2][2];
#pragma unroll
  for (int kk = 0; kk < 2; ++kk)
#pragma unroll
    for (int mt = 0; mt < 2; ++mt)
      aq[kk][mt] = *(const f16x8*)&gqb[(long)(w * 32 + mt * 16 + l15) * 64 + kk * 32 + l4 * 8];

  f32x4 acc[2][4];
#pragma unroll
  for (int i = 0; i < 2; ++i)
#pragma unroll
    for (int j = 0; j < 4; ++j) acc[i][j] = f32x4{0.f, 0.f, 0.f, 0.f};
#pragma unroll
  for (int kk = 0; kk < 2; ++kk)
#pragma unroll
    for (int mt = 0; mt < 2; ++mt)
#pragma unroll
      for (int nt = 0; nt < 4; ++nt)
        acc[mt][nt] = __builtin_amdgcn_mfma_f32_16x16x32_f16(aq[kk][mt], br[kk][nt], acc[mt][nt], 0, 0, 0);

#pragma unroll
  for (int mt = 0; mt < 2; ++mt)
#pragma unroll
    for (int r = 0; r < 4; ++r) {
      const float v0 = acc[mt][0][r], v1 = acc[mt][1][r];
      const float v2 = acc[mt][2][r], v3 = acc[mt][3][r];
      unsigned int k0 = (__float_as_uint(fabsf(v0)) & ~63u) | (unsigned int)(63 - l15);
      unsigned int k1 = (__float_as_uint(fabsf(v1)) & ~63u) | (unsigned int)(47 - l15);
      unsigned int k2 = (__float_as_uint(fabsf(v2)) & ~63u) | (unsigned int)(31 - l15);
      unsigned int k3 = (__float_as_uint(fabsf(v3)) & ~63u) | (unsigned int)(15 - l15);
      float ss = v0 * v0 + v1 * v1 + v2 * v2 + v3 * v3;
#pragma unroll
      for (int m = 1; m < 16; m <<= 1) ss += __shfl_xor(ss, m);

      unsigned int mk = max(max(k0, k1), max(k2, k3));
#pragma unroll
      for (int m = 1; m < 16; m <<= 1) mk = max(mk, (unsigned int)__shfl_xor((int)mk, m));
      const unsigned int key1 = mk;
      const int col1 = 63 - (int)(key1 & 63u);
      const float m1f = __uint_as_float(key1 & ~63u);
      const int nt1 = col1 >> 4;
      const float vsel = (nt1 == 0) ? v0 : (nt1 == 1) ? v1 : (nt1 == 2) ? v2 : v3;
      const bool owner = (col1 & 15) == l15;
      const u64 bal = __ballot(owner && (vsel < 0.f));
      const int neg = (int)((bal >> (l4 * 16 + (col1 & 15))) & 1ull);
      const int bucket = col1 + (neg << 6);
      if (owner) {
        if (nt1 == 0) k0 = 0; else if (nt1 == 1) k1 = 0;
        else if (nt1 == 2) k2 = 0; else k3 = 0;
      }
      mk = max(max(k0, k1), max(k2, k3));
#pragma unroll
      for (int m = 1; m < 16; m <<= 1) mk = max(mk, (unsigned int)__shfl_xor((int)mk, m));
      const int col2 = 63 - (int)(mk & 63u);
      const float m2f = __uint_as_float(mk & ~63u);
      {
        const int nt2 = col2 >> 4;
        if ((col2 & 15) == l15) {
          if (nt2 == 0) k0 = 0; else if (nt2 == 1) k1 = 0;
          else if (nt2 == 2) k2 = 0; else k3 = 0;
        }
      }
      mk = max(max(k0, k1), max(k2, k3));
#pragma unroll
      for (int m = 1; m < 16; m <<= 1) mk = max(mk, (unsigned int)__shfl_xor((int)mk, m));
      const int col3 = 63 - (int)(mk & 63u);

      if (l15 == 0) {
        const int row = w * 32 + mt * 16 + l4 * 4 + r;
        const int bht = bh * 4096 + t0 + row;
        const float margin = m1f - m2f;
        const float rms = sqrtf(ss * (1.f / 64.f));
        const int flag = (margin < 0.015f * rms) ? 1 : 0;
        buckets[bht] = bucket | (col2 << 8) | (col3 << 16) | (flag << 24);
      }
    }
}

// ---------------------------------------------------------------------------
// fixup2: scan flag bit; per-wave ballot compaction; exact fp32 re-eval.
// h1 recomputed as exact fp32 LN(x) per flagged row.
// ---------------------------------------------------------------------------
__global__ __launch_bounds__(256)
void fixup2_kernel(const float* __restrict__ x, const float* __restrict__ gam,
                   const float* __restrict__ bet, const float* __restrict__ WrT,
                   int* __restrict__ buckets)
{
  const int wid = (blockIdx.x * 256 + threadIdx.x) >> 6;   // 0..1023
  const int lane = threadIdx.x & 63;
  for (int batch = 0; batch < 4; ++batch) {
    const int base = wid * 256 + batch * 64;
    const int packed = buckets[base + lane];
    u64 bal = __ballot((packed >> 24) & 1);
    while (bal) {
      const int i = (int)__ffsll((long long)bal) - 1;
      bal &= bal - 1;
      const int row = base + i;
      const int pk = __shfl(packed, i);
      const int h = (row >> 12) & 7;
      const long hrow = (long)(row >> 15) * 4096 + (row & 4095);
      const float4* xp = (const float4*)(x + hrow * 512 + lane * 8);
      const float4 a = xp[0], b = xp[1];
      float xv[8] = {a.x, a.y, a.z, a.w, b.x, b.y, b.z, b.w};
      float s = 0.f;
#pragma unroll
      for (int k = 0; k < 8; ++k) s += xv[k];
#pragma unroll
      for (int m = 32; m; m >>= 1) s += __shfl_xor(s, m);
      const float mean = s * (1.f / 512.f);
      float vs = 0.f;
#pragma unroll
      for (int k = 0; k < 8; ++k) { const float d = xv[k] - mean; vs += d * d; }
#pragma unroll
      for (int m = 32; m; m >>= 1) vs += __shfl_xor(vs, m);
      const float rstd = 1.f / sqrtf(vs * (1.f / 512.f) + 1e-5f);
      const float4* gp = (const float4*)(gam + lane * 8);
      const float4* bp = (const float4*)(bet + lane * 8);
      const float4 g0 = gp[0], g1 = gp[1];
      const float4 bb0 = bp[0], bb1 = bp[1];
      const float gg[8] = {g0.x, g0.y, g0.z, g0.w, g1.x, g1.y, g1.z, g1.w};
      const float bb[8] = {bb0.x, bb0.y, bb0.z, bb0.w, bb1.x, bb1.y, bb1.z, bb1.w};
      float h1[8];
#pragma unroll
      for (int k = 0; k < 8; ++k) h1[k] = (xv[k] - mean) * rstd * gg[k] + bb[k];
      const int cols[3] = { pk & 63, (pk >> 8) & 63, (pk >> 16) & 63 };
      float best = -1e30f; int bi = 999;
#pragma unroll
      for (int c = 0; c < 3; ++c) {
        const int cc = cols[c];
        const float* wp = WrT + ((long)(h * 64 + cc)) * 512 + lane * 8;
        const float4 w0 = *(const float4*)wp;
        const float4 w1 = *(const float4*)(wp + 4);
        float sdot = h1[0] * w0.x + h1[1] * w0.y + h1[2] * w0.z + h1[3] * w0.w
                   + h1[4] * w1.x + h1[5] * w1.y + h1[6] * w1.z + h1[7] * w1.w;
#pragma unroll
        for (int m = 32; m; m >>= 1) sdot += __shfl_xor(sdot, m);
        if (sdot > best || (sdot == best && cc < bi)) { best = sdot; bi = cc; }
        const float ns = -sdot; const int ni = 64 + cc;
        if (ns > best || (ns == best && ni < bi)) { best = ns; bi = ni; }
      }
      if (lane == 0) buckets[row] = bi;
    }
  }
}

// ---------------------------------------------------------------------------
// Stable counting sort by (bucket, t) per bh. 512 threads / 8 waves.
// sticker[pos] = original t.
// ---------------------------------------------------------------------------
__global__ __launch_bounds__(512)
void sort_kernel(const int* __restrict__ buckets, int* __restrict__ sticker)
{
  __shared__ int bkt[4096];
  __shared__ unsigned int cnts[64][128];
  __shared__ unsigned char rnk[4096];
  __shared__ int tot[128];
  __shared__ int base[128];
  const int bh = blockIdx.x;
  const int tid = threadIdx.x;
  const int lane = tid & 63, wv = tid >> 6;   // wv 0..7

  for (int i = tid; i < 4096; i += 512) bkt[i] = buckets[(long)bh * 4096 + i] & 127;
  for (int i = tid; i < 64 * 128; i += 512) ((unsigned int*)cnts)[i] = 0u;
  __syncthreads();

  for (int it = 0; it < 8; ++it) {
    const int c = wv * 8 + it;
    const int t = c * 64 + lane;
    const int b = bkt[t];
    unsigned long long m = ~0ull;
#pragma unroll
    for (int k = 0; k < 7; ++k) {
      const bool bit = (b >> k) & 1;
      const unsigned long long bal = __ballot(bit);
      m &= bit ? bal : ~bal;
    }
    const int rk = (int)__popcll(m & ((1ull << lane) - 1ull));
    rnk[t] = (unsigned char)rk;
    if (rk == 0) cnts[c][b] = (unsigned int)__popcll(m);
  }
  __syncthreads();

  if (tid < 128) {
    unsigned int run = 0;
    for (int c = 0; c < 64; ++c) {
      const unsigned int x = cnts[c][tid];
      cnts[c][tid] = run;
      run += x;
    }
    tot[tid] = (int)run;
  }
  __syncthreads();
  if (tid == 0) {
    int run = 0;
    for (int b = 0; b < 128; ++b) { base[b] = run; run += tot[b]; }
  }
  __syncthreads();

  for (int it = 0; it < 8; ++it) {
    const int c = wv * 8 + it;
    const int t = c * 64 + lane;
    const int b = bkt[t];
    const int pos = base[b] + (int)cnts[c][b] + (int)rnk[t];
    sticker[(long)bh * 4096 + pos] = t;
  }
}

// ---------------------------------------------------------------------------
// LSH attention, gather version. Block = 256 thr / 4 waves / 4 chunks.
// XCD-bijective block swizzle: all 32 cg-blocks of one bh share an XCD.
// ---------------------------------------------------------------------------
__global__ __launch_bounds__(256)
void attn2_kernel(const f16* __restrict__ gqk, const f16* __restrict__ gv,
                  const int* __restrict__ sticker, f16* __restrict__ o)
{
  __shared__ __align__(16) f16 sqk[160 * 64];     // granule-XOR swizzled
  __shared__ __align__(16) f16 sVT[64 * 168];     // [d][key 0..159]
  __shared__ __align__(16) f16 sP[4][32 * 72];
  __shared__ float rnorm[160];
  __shared__ int st[160];

  const int tid = threadIdx.x, lane = tid & 63, w = tid >> 6;
  int lid = blockIdx.y * 32 + blockIdx.x;         // nwg = 2048, %8 == 0
  lid = (lid & 7) * 256 + (lid >> 3);             // bijective XCD chunking
  const int cg = lid & 31, bh = lid >> 5;
  const int b = bh >> 3, h = bh & 7;
  const int p0 = cg * 128 - 32;
  const int l15 = lane & 15, l4 = lane >> 4;

  if (tid < 160) st[tid] = sticker[(long)bh * 4096 + ((p0 + tid) & 4095)] & 4095;
  __syncthreads();

  const f16* gqb = gqk + (long)bh * 4096 * 64;
#pragma unroll
  for (int it = 0; it < 5; ++it) {
    const int idx = it * 256 + tid;
    const int row = idx >> 3, ch = idx & 7;
    const int gsrc = ch ^ (row & 7);
    gload16(gqb + (long)st[row] * 64 + gsrc * 8, &sqk[idx * 8]);
  }

  const f16* gvb = gv + (long)bh * 4096 * 64;
  f16x8 va[5];
#pragma unroll
  for (int i = 0; i < 5; ++i) {
    const int row = w * 40 + i * 8 + (lane >> 3);
    va[i] = *(const f16x8*)&gvb[(long)st[row] * 64 + (lane & 7) * 8];
  }
#pragma unroll
  for (int i = 0; i < 5; ++i) {
    const int row = w * 40 + i * 8 + (lane >> 3);
    const int d0 = (lane & 7) * 8;
#pragma unroll
    for (int e = 0; e < 8; ++e) sVT[(d0 + e) * 168 + row] = va[i][e];
  }
  __syncthreads();

  if (tid < 160) {
    float s = 0.f;
#pragma unroll
    for (int g = 0; g < 8; ++g) {
      const f16x8 v = *(const f16x8*)&sqk[tid * 64 + ((g ^ (tid & 7)) << 3)];
#pragma unroll
      for (int e = 0; e < 8; ++e) { const float f = (float)v[e]; s += f * f; }
    }
    rnorm[tid] = 1.f / fmaxf(sqrtf(s), 1e-12f);
  }
  __syncthreads();

  f32x4 acc[2][4];
#pragma unroll
  for (int i = 0; i < 2; ++i)
#pragma unroll
    for (int j = 0; j < 4; ++j) acc[i][j] = f32x4{0.f, 0.f, 0.f, 0.f};

#pragma unroll
  for (int kk = 0; kk < 2; ++kk) {
    f16x8 aq[2], bk[4];
#pragma unroll
    for (int mt = 0; mt < 2; ++mt) {
      const int row = 32 + w * 32 + mt * 16 + l15;
      const int g = kk * 4 + l4;
      aq[mt] = *(const f16x8*)&sqk[row * 64 + ((g ^ (row & 7)) << 3)];
    }
#pragma unroll
    for (int nt = 0; nt < 4; ++nt) {
      const int row = w * 32 + nt * 16 + l15;
      const int g = kk * 4 + l4;
      bk[nt] = *(const f16x8*)&sqk[row * 64 + ((g ^ (row & 7)) << 3)];
    }
#pragma unroll
    for (int mt = 0; mt < 2; ++mt)
#pragma unroll
      for (int nt = 0; nt < 4; ++nt)
        acc[mt][nt] = __builtin_amdgcn_mfma_f32_16x16x32_f16(aq[mt], bk[nt], acc[mt][nt], 0, 0, 0);
  }

  float rn[4];
#pragma unroll
  for (int nt = 0; nt < 4; ++nt) rn[nt] = rnorm[w * 32 + nt * 16 + l15];

  float pinv[2][4];
#pragma unroll
  for (int mt = 0; mt < 2; ++mt)
#pragma unroll
    for (int r = 0; r < 4; ++r) {
      const int row_i = mt * 16 + l4 * 4 + r;
      float mx = -1e30f;
#pragma unroll
      for (int nt = 0; nt < 4; ++nt) {
        float v = acc[mt][nt][r] * 0.125f * rn[nt];
        if (nt * 16 + l15 == row_i + 32) v = -5e4f;
        acc[mt][nt][r] = v;
        mx = fmaxf(mx, v);
      }
#pragma unroll
      for (int m = 8; m; m >>= 1) mx = fmaxf(mx, __shfl_xor(mx, m));
      float ssum = 0.f;
#pragma unroll
      for (int nt = 0; nt < 4; ++nt) {
        const float pe = expf(acc[mt][nt][r] - mx);
        ssum += pe;
        sP[w][row_i * 72 + nt * 16 + l15] = (f16)pe;
      }
#pragma unroll
      for (int m = 8; m; m >>= 1) ssum += __shfl_xor(ssum, m);
      pinv[mt][r] = 1.f / ssum;
    }
  __syncthreads();

  f32x4 pacc[2][4];
#pragma unroll
  for (int i = 0; i < 2; ++i)
#pragma unroll
    for (int j = 0; j < 4; ++j) pacc[i][j] = f32x4{0.f, 0.f, 0.f, 0.f};

#pragma unroll
  for (int kk = 0; kk < 2; ++kk) {
    f16x8 ap[2], bv[4];
#pragma unroll
    for (int mt = 0; mt < 2; ++mt)
      ap[mt] = *(const f16x8*)&sP[w][(mt * 16 + l15) * 72 + kk * 32 + l4 * 8];
#pragma unroll
    for (int nt = 0; nt < 4; ++nt)
      bv[nt] = *(const f16x8*)&sVT[(nt * 16 + l15) * 168 + w * 32 + kk * 32 + l4 * 8];
#pragma unroll
    for (int mt = 0; mt < 2; ++mt)
#pragma unroll
      for (int nt = 0; nt < 4; ++nt)
        pacc[mt][nt] = __builtin_amdgcn_mfma_f32_16x16x32_f16(ap[mt], bv[nt], pacc[mt][nt], 0, 0, 0);
  }

  const long ob = (long)b * 4096 * 512 + h * 64;
#pragma unroll
  for (int mt = 0; mt < 2; ++mt)
#pragma unroll
    for (int r = 0; r < 4; ++r) {
      const int row_i = mt * 16 + l4 * 4 + r;
      const long t = st[32 + w * 32 + row_i];
      const float sc = pinv[mt][r];
#pragma unroll
      for (int nt = 0; nt < 4; ++nt)
        o[ob + t * 512 + nt * 16 + l15] = (f16)(pacc[mt][nt][r] * sc);
    }
}

// ---------------------------------------------------------------------------
extern "C" void kernel_launch(void* const* d_in, const int* in_sizes, int n_in,
                              void* d_out, int out_size, void* d_ws, size_t ws_size,
                              hipStream_t stream)
{
  const float* x     = (const float*)d_in[0];
  const float* w_qk  = (const float*)d_in[1];
  const float* w_v   = (const float*)d_in[2];
  const float* w_out = (const float*)d_in[3];
  const float* b_out = (const float*)d_in[4];
  const float* ln1g  = (const float*)d_in[5];
  const float* ln1b  = (const float*)d_in[6];
  const float* w_ff1 = (const float*)d_in[7];
  const float* b_ff1 = (const float*)d_in[8];
  const float* w_ff2 = (const float*)d_in[9];
  const float* b_ff2 = (const float*)d_in[10];
  const float* ln2g  = (const float*)d_in[11];
  const float* ln2b  = (const float*)d_in[12];
  const float* rot   = (const float*)d_in[13];
  float* out = (float*)d_out;

  char* ws = (char*)d_ws;
  // [0,32M):  hh (ln1 out, dead after qkv) -> o_buf (attn2 out, dead after
  //           wout) -> h2 (ln16 out, dead after FFN1 chunks)
  // [32,64M): xh (ln1 out) -> sxy (wout EPI12, in-place over xh; live to end)
  // [64,128M): gqk[64,96M)+gv[96,128M) (dead after attn2) -> y1h[64,96M)
  //            (wout out, dead after ln16) -> abuf[64,128M) (FFN mid)
  // [128M,+9.1M): weights + WrT + buckets + sticker + rotTh
  f16* hh     = (f16*)ws;
  f16* o_buf  = (f16*)ws;
  f16* h2     = (f16*)ws;
  f16* xh     = (f16*)(ws + 33554432);
  f16* sxy    = (f16*)(ws + 33554432);
  f16* gqk    = (f16*)(ws + 67108864);
  f16* gv     = (f16*)(ws + 100663296);
  f16* y1h    = (f16*)(ws + 67108864);
  f16* abuf   = (f16*)(ws + 67108864);
  char* W0 = ws + 134217728;
  f16* wqkvT = (f16*)W0;                        // [1024][512]
  f16* woutT = (f16*)(W0 + 1048576);            // [512][512]
  f16* wff1T = (f16*)(W0 + 1572864);            // [2048][512]
  f16* wff2T = (f16*)(W0 + 3670016);            // [512][2048]
  float* WrT = (float*)(W0 + 5767168);          // [512][512] fp32
  int* buckets = (int*)(W0 + 6815744);          // [64][4096]
  int* sticker = (int*)(W0 + 7864320);          // [64][4096]
  f16* rotTh   = (f16*)(W0 + 8912896);          // [64][64]

  const dim3 b256(256);
  const dim3 b512(512);
  // all 5 weight transposes in one launch
  transpose_all<<<dim3(2816), b256, 0, stream>>>(w_qk, w_v, w_out, w_ff1, w_ff2,
      wqkvT, woutT, wff1T, wff2T);
  whash_f32<<<dim3(512, 2), b256, 0, stream>>>(w_qk, rot, WrT, rotTh);
  // LN1: hh = f16 LN(x) (stride 512); xh = f16 x
  ln_x16_kernel<<<dim3(8192), b256, 0, stream>>>(x, ln1g, ln1b, hh, xh);
  // qkv = h1 @ [w_qk | w_v], head-major f16 out (8-phase 256^2)
  gemm256<17><<<dim3(4, 128), b512, 0, stream>>>(hh, 512, wqkvT, 512, 512, 1024,
      nullptr, gqk, gv, nullptr, nullptr);
  // approx hash (no atomics) + exact fixup (recomputes LN from x) + sort + attn
  rhash4_kernel<<<dim3(2048), b256, 0, stream>>>(gqk, rotTh, buckets);
  fixup2_kernel<<<dim3(256), b256, 0, stream>>>(x, ln1g, ln1b, WrT, buckets);
  sort_kernel<<<dim3(64), b512, 0, stream>>>(buckets, sticker);
  attn2_kernel<<<dim3(32, 64), b256, 0, stream>>>(gqk, gv, sticker, o_buf);
  // wout: y1h = xh + o @ w_out + b_out;  sxy = xh + 0.5*(c+bias) (in-place)
  gemm256<12><<<dim3(2, 128), b512, 0, stream>>>(o_buf, 512, woutT, 512, 512, 512,
      nullptr, sxy, y1h, b_out, xh);
  // ln2: h2 = LN(y1h)  (f16 input)
  ln16_kernel<<<dim3(8192), b256, 0, stream>>>(y1h, ln2g, ln2b, h2);
  // FFN in 2 row-chunks of 16384 (abuf = [16384][2048] = 64MB)
  for (int c = 0; c < 2; ++c) {
    const long roff = (long)c * 16384;
    gemm256<13><<<dim3(8, 64), b512, 0, stream>>>(h2 + roff * 512, 512, wff1T, 512,
        512, 2048, nullptr, abuf, nullptr, b_ff1, nullptr);
    ffn2_8ph<<<dim3(4, 64), b512, 0, stream>>>(abuf, wff2T, sxy + roff * 512,
        b_ff2, out + roff * 512);
  }
}